// Round 10
// baseline (10246.312 us; speedup 1.0000x reference)
//
#include <hip/hip_runtime.h>

typedef unsigned short u16;

// Problem constants
#define CC   256
#define HH   4
#define HD   64
#define LL   6
#define FCD  1024
#define OUTD 192
#define WSZ  4
#define BB   8
#define TT   1024
#define BT   8192   // B*T

// Output flat offsets (fp32 elements)
#define OFF_XBCT 0
#define OFF_M    2097152
#define OFF_LOGS 3670016
#define OFF_MASK 5242880
#define OUT_TOTAL 5251072

__device__ __forceinline__ float bf2f(u16 u) {
  union { unsigned int i; float f; } v; v.i = ((unsigned int)u) << 16; return v.f;
}
__device__ __forceinline__ u16 f2bf(float f) {
  union { float f; unsigned int i; } v; v.f = f;
  unsigned int x = v.i;
  return (u16)((x + 0x7fffu + ((x >> 16) & 1u)) >> 16);
}
// typed internal loads/stores (fp32 math everywhere)
__device__ __forceinline__ void ldv4(const float* p, float* o) {
  float4 v = *reinterpret_cast<const float4*>(p);
  o[0] = v.x; o[1] = v.y; o[2] = v.z; o[3] = v.w;
}
__device__ __forceinline__ void ldv4(const u16* p, float* o) {
  ushort4 v = *reinterpret_cast<const ushort4*>(p);
  o[0] = bf2f(v.x); o[1] = bf2f(v.y); o[2] = bf2f(v.z); o[3] = bf2f(v.w);
}
__device__ __forceinline__ float ld_e(const float* p) { return *p; }
__device__ __forceinline__ float ld_e(const u16* p)   { return bf2f(*p); }
__device__ __forceinline__ void st_e(float* p, float v) { *p = v; }
__device__ __forceinline__ void st_e(u16* p, float v)   { *p = f2bf(v); }

// ---------------- Embedding: X[bt,c] = emb[tok[bt], c] * 16 ----------------
__global__ __launch_bounds__(256) void embed_k(
    const float* __restrict__ emb, const int* __restrict__ tokens,
    float* __restrict__ X)
{
  const int i = blockIdx.x * 256 + threadIdx.x;   // BT*CC
  const int bt = i >> 8;
  const int c  = i & (CC - 1);
  X[i] = emb[(size_t)tokens[bt] * CC + c] * 16.0f;
}

// ---------------- Tiled GEMM: C = ps*(A @ W [+ bias]), opt relu/accum ----------------
// A: M x K row-major (lda == K), fp32 or bf16. W: fp32, row-major K x ldb (pre-offset
// to the logical column origin). bias: fp32 (pre-offset) or nullptr.
// C: row stride ldc. Grid: (N/64, M/64), 256 threads.
#define BM 64
#define BN 64
#define BK 16
template <typename AT, typename CT>
__global__ __launch_bounds__(256) void gemm_k(
    const AT* __restrict__ A, const float* __restrict__ W, int ldb,
    const float* __restrict__ bias, CT* __restrict__ C, int ldc,
    int K, float ps, int relu, int accum)
{
  __shared__ float As[BK][BM + 1];
  __shared__ float Bs[BK][BN + 1];
  const int tid = threadIdx.x;
  const int bm = blockIdx.y * BM;
  const int bn = blockIdx.x * BN;
  const int tr = (tid >> 4) << 2;
  const int tc = (tid & 15) << 2;
  const int ar = tid >> 2;
  const int ac = (tid & 3) << 2;
  float acc[4][4] = {{0.0f}};
  float tmp[4];
  for (int k0 = 0; k0 < K; k0 += BK) {
    ldv4(A + (size_t)(bm + ar) * K + (k0 + ac), tmp);
    As[ac + 0][ar] = tmp[0]; As[ac + 1][ar] = tmp[1];
    As[ac + 2][ar] = tmp[2]; As[ac + 3][ar] = tmp[3];
    const int rk = tid >> 4;
    const int cn = (tid & 15) << 2;
    ldv4(W + (size_t)(k0 + rk) * ldb + (bn + cn), tmp);
    Bs[rk][cn + 0] = tmp[0]; Bs[rk][cn + 1] = tmp[1];
    Bs[rk][cn + 2] = tmp[2]; Bs[rk][cn + 3] = tmp[3];
    __syncthreads();
#pragma unroll
    for (int kk = 0; kk < BK; ++kk) {
      const float a0 = As[kk][tr + 0], a1 = As[kk][tr + 1];
      const float a2 = As[kk][tr + 2], a3 = As[kk][tr + 3];
      const float b0 = Bs[kk][tc + 0], b1 = Bs[kk][tc + 1];
      const float b2 = Bs[kk][tc + 2], b3 = Bs[kk][tc + 3];
      acc[0][0] += a0 * b0; acc[0][1] += a0 * b1; acc[0][2] += a0 * b2; acc[0][3] += a0 * b3;
      acc[1][0] += a1 * b0; acc[1][1] += a1 * b1; acc[1][2] += a1 * b2; acc[1][3] += a1 * b3;
      acc[2][0] += a2 * b0; acc[2][1] += a2 * b1; acc[2][2] += a2 * b2; acc[2][3] += a2 * b3;
      acc[3][0] += a3 * b0; acc[3][1] += a3 * b1; acc[3][2] += a3 * b2; acc[3][3] += a3 * b3;
    }
    __syncthreads();
  }
#pragma unroll
  for (int i = 0; i < 4; ++i) {
    const size_t row = (size_t)(bm + tr + i);
#pragma unroll
    for (int j = 0; j < 4; ++j) {
      const int col = bn + tc + j;
      float vv = acc[i][j];
      if (bias) vv += bias[col];
      vv *= ps;
      if (relu) vv = fmaxf(vv, 0.0f);
      const size_t ci = row * ldc + col;
      if (accum) vv += ld_e(C + ci);
      st_e(C + ci, vv);
    }
  }
}

// ---------------- Attention, one head, one block per (b, q) ----------------
// Qh/Kh/Vh: (BT, 64) bf16 compact, Q pre-scaled 0.125. rk/rv: fp32 (9,64) slices.
// Ob: fp32 (BT, 256), write columns [hcol, hcol+64).
__global__ __launch_bounds__(256) void attn_k(
    const u16* __restrict__ Qh, const u16* __restrict__ Kh,
    const u16* __restrict__ Vh, const float* __restrict__ rk,
    const float* __restrict__ rv, const int* __restrict__ xlen,
    float* __restrict__ Ob, int hcol)
{
  __shared__ float qv[HD];
  __shared__ float p[TT];
  __shared__ float red[256];
  __shared__ float psum[4][HD];
  const int bq   = blockIdx.x;            // b*1024 + q
  const int b    = bq >> 10;
  const int q    = bq & (TT - 1);
  const int tid  = threadIdx.x;
  const int len  = xlen[b];
  if (tid < HD) qv[tid] = bf2f(Qh[(size_t)bq * HD + tid]);
  __syncthreads();
  const int qok = (q < len) ? 1 : 0;
  float tmp[4];
  for (int kk = tid; kk < TT; kk += 256) {
    const u16* kr = Kh + ((size_t)((b << 10) + kk)) * HD;
    float s = 0.0f;
#pragma unroll
    for (int d = 0; d < HD; d += 4) {
      ldv4(kr + d, tmp);
      s += qv[d] * tmp[0] + qv[d + 1] * tmp[1] + qv[d + 2] * tmp[2] + qv[d + 3] * tmp[3];
    }
    const int r = kk - q;
    if (r >= -WSZ && r <= WSZ) {
      const float* rp = rk + (r + WSZ) * HD;
      float s2 = 0.0f;
#pragma unroll
      for (int d = 0; d < HD; ++d) s2 += qv[d] * rp[d];
      s += s2;
    }
    if (!qok || kk >= len) s = -10000.0f;
    p[kk] = s;
  }
  __syncthreads();
  float lm = -3.0e38f;
  for (int kk = tid; kk < TT; kk += 256) lm = fmaxf(lm, p[kk]);
  red[tid] = lm; __syncthreads();
  for (int s2 = 128; s2 > 0; s2 >>= 1) {
    if (tid < s2) red[tid] = fmaxf(red[tid], red[tid + s2]);
    __syncthreads();
  }
  const float mx = red[0];
  __syncthreads();
  float ls = 0.0f;
  for (int kk = tid; kk < TT; kk += 256) {
    const float e = expf(p[kk] - mx);
    p[kk] = e; ls += e;
  }
  red[tid] = ls; __syncthreads();
  for (int s2 = 128; s2 > 0; s2 >>= 1) {
    if (tid < s2) red[tid] += red[tid + s2];
    __syncthreads();
  }
  const float inv = 1.0f / red[0];
  __syncthreads();
  for (int kk = tid; kk < TT; kk += 256) p[kk] *= inv;
  __syncthreads();
  const int d = tid & (HD - 1);
  const int part = tid >> 6;
  float o = 0.0f;
  const int kb = part * (TT / 4);
  for (int kk = kb; kk < kb + TT / 4; ++kk)
    o += p[kk] * bf2f(Vh[((size_t)((b << 10) + kk)) * HD + d]);
  psum[part][d] = o;
  __syncthreads();
  if (tid < HD) {
    float oo = psum[0][tid] + psum[1][tid] + psum[2][tid] + psum[3][tid];
#pragma unroll
    for (int r = -WSZ; r <= WSZ; ++r) {
      const int kk = q + r;
      if (kk >= 0 && kk < TT) oo += p[kk] * rv[(r + WSZ) * HD + tid];
    }
    Ob[(size_t)bq * CC + hcol + tid] = oo;
  }
}

// ---------------- Residual add + LayerNorm (+ optional mask) ----------------
__global__ __launch_bounds__(256) void addln_k(
    float* __restrict__ X, const float* __restrict__ R,
    const float* __restrict__ g, const float* __restrict__ be,
    const int* __restrict__ xlen, int am)
{
  __shared__ float red[256];
  const int row = blockIdx.x;   // b*1024 + t
  const int tid = threadIdx.x;
  const int b = row >> 10;
  const int t = row & (TT - 1);
  const size_t base = (size_t)row * CC;
  const float v = X[base + tid] + R[base + tid];
  red[tid] = v; __syncthreads();
  for (int s2 = 128; s2 > 0; s2 >>= 1) {
    if (tid < s2) red[tid] += red[tid + s2];
    __syncthreads();
  }
  const float mean = red[0] * (1.0f / CC);
  __syncthreads();
  const float dv = v - mean;
  red[tid] = dv * dv; __syncthreads();
  for (int s2 = 128; s2 > 0; s2 >>= 1) {
    if (tid < s2) red[tid] += red[tid + s2];
    __syncthreads();
  }
  const float var = red[0] * (1.0f / CC);
  float y = dv * rsqrtf(var + 1e-5f) * g[tid] + be[tid];
  if (am && t >= xlen[b]) y = 0.0f;
  X[base + tid] = y;
}

// ---------------- Final projection -> fp32 m/logs, masked ----------------
// A: X (BT x 256 fp32). W: proj_w (384 x 256) row-major N x K.
__global__ __launch_bounds__(256) void proj_k(
    const float* __restrict__ A, const float* __restrict__ W,
    const float* __restrict__ bias, const int* __restrict__ xlen,
    float* __restrict__ out)
{
  __shared__ float As[BK][BM + 1];
  __shared__ float Bs[BK][BN + 1];
  const int tid = threadIdx.x;
  const int bm = blockIdx.y * BM;
  const int bn = blockIdx.x * BN;
  const int tr = (tid >> 4) << 2;
  const int tc = (tid & 15) << 2;
  const int ar = tid >> 2;
  const int ac = (tid & 3) << 2;
  float acc[4][4] = {{0.0f}};
  float tmp[4];
  for (int k0 = 0; k0 < CC; k0 += BK) {
    ldv4(A + (size_t)(bm + ar) * CC + (k0 + ac), tmp);
    As[ac + 0][ar] = tmp[0]; As[ac + 1][ar] = tmp[1];
    As[ac + 2][ar] = tmp[2]; As[ac + 3][ar] = tmp[3];
    const int nn = tid >> 2;
    const int kx = (tid & 3) << 2;
    ldv4(W + (size_t)(bn + nn) * CC + (k0 + kx), tmp);
    Bs[kx + 0][nn] = tmp[0]; Bs[kx + 1][nn] = tmp[1];
    Bs[kx + 2][nn] = tmp[2]; Bs[kx + 3][nn] = tmp[3];
    __syncthreads();
#pragma unroll
    for (int kk = 0; kk < BK; ++kk) {
      const float a0 = As[kk][tr + 0], a1 = As[kk][tr + 1];
      const float a2 = As[kk][tr + 2], a3 = As[kk][tr + 3];
      const float b0 = Bs[kk][tc + 0], b1 = Bs[kk][tc + 1];
      const float b2 = Bs[kk][tc + 2], b3 = Bs[kk][tc + 3];
      acc[0][0] += a0 * b0; acc[0][1] += a0 * b1; acc[0][2] += a0 * b2; acc[0][3] += a0 * b3;
      acc[1][0] += a1 * b0; acc[1][1] += a1 * b1; acc[1][2] += a1 * b2; acc[1][3] += a1 * b3;
      acc[2][0] += a2 * b0; acc[2][1] += a2 * b1; acc[2][2] += a2 * b2; acc[2][3] += a2 * b3;
      acc[3][0] += a3 * b0; acc[3][1] += a3 * b1; acc[3][2] += a3 * b2; acc[3][3] += a3 * b3;
    }
    __syncthreads();
  }
#pragma unroll
  for (int i = 0; i < 4; ++i) {
    const int row = bm + tr + i;
    const int b = row >> 10;
    const int t = row & (TT - 1);
    const int len = xlen[b];
#pragma unroll
    for (int j = 0; j < 4; ++j) {
      const int o = bn + tc + j;
      float vv = acc[i][j] + bias[o];
      if (t >= len) vv = 0.0f;
      const size_t dst = (o < OUTD)
          ? (size_t)OFF_M    + ((size_t)b * OUTD + o) * TT + t
          : (size_t)OFF_LOGS + ((size_t)b * OUTD + (o - OUTD)) * TT + t;
      out[dst] = vv;
    }
  }
}

// ---------------- Output packing (fp32) ----------------
__global__ __launch_bounds__(256) void pack_xbct_k(
    const float* __restrict__ X, float* __restrict__ out)
{
  const int i = blockIdx.x * 256 + threadIdx.x;  // b*(C*T) + c*T + t
  const int b = i >> 18;
  const int c = (i >> 10) & (CC - 1);
  const int t = i & (TT - 1);
  out[OFF_XBCT + i] = X[((size_t)b << 18) + ((size_t)t << 8) + c];
}

__global__ __launch_bounds__(256) void pack_mask_k(
    const int* __restrict__ xlen, float* __restrict__ out)
{
  const int i = blockIdx.x * 256 + threadIdx.x;  // B*T
  const int b = i >> 10;
  const int t = i & (TT - 1);
  out[OFF_MASK + i] = (t < xlen[b]) ? 1.0f : 0.0f;
}

extern "C" void kernel_launch(void* const* d_in, const int* in_sizes, int n_in,
                              void* d_out, int out_size, void* d_ws, size_t ws_size,
                              hipStream_t stream)
{
  (void)in_sizes; (void)n_in; (void)out_size; (void)ws_size;
  const float* emb   = (const float*)d_in[0];
  const float* Wq    = (const float*)d_in[1];
  const float* Wk    = (const float*)d_in[2];
  const float* Wv    = (const float*)d_in[3];
  const float* Wo    = (const float*)d_in[4];
  const float* bq    = (const float*)d_in[5];
  const float* bk    = (const float*)d_in[6];
  const float* bv    = (const float*)d_in[7];
  const float* bo    = (const float*)d_in[8];
  const float* relk  = (const float*)d_in[9];
  const float* relv  = (const float*)d_in[10];
  const float* ln1g  = (const float*)d_in[11];
  const float* ln1b  = (const float*)d_in[12];
  const float* ln2g  = (const float*)d_in[13];
  const float* ln2b  = (const float*)d_in[14];
  const float* W1    = (const float*)d_in[15];
  const float* b1    = (const float*)d_in[16];
  const float* W2    = (const float*)d_in[17];
  const float* b2    = (const float*)d_in[18];
  const float* projw = (const float*)d_in[19];
  const float* projb = (const float*)d_in[20];
  const int*   tokens = (const int*)d_in[21];
  const int*   xlen   = (const int*)d_in[22];
  float* out = (float*)d_out;   // OUTPUT IS FP32 (reference output dtype)

  // ws (12 MB, proven available): X fp32 (8MB) | pool (4MB): QKV bf16 or Hc bf16
  float* X  = (float*)d_ws;
  u16* pool = (u16*)(X + (size_t)BT * CC);
  u16* Qh = pool;                          // BT*64 bf16 (1MB)
  u16* Kh = pool + (size_t)BT * HD;
  u16* Vh = pool + 2 * (size_t)BT * HD;
  u16* Hc = pool;                          // BT*256 bf16 (4MB), aliases QKV (disjoint phases)
  // d_out (21MB fp32) scratch, dead before the final writes that cover it:
  float* Ob = out + OFF_XBCT;              // BT*256 fp32 (8MB) — overwritten by pack_xbct
  float* T5 = out + OFF_M;                 // BT*256 fp32 (8MB) — overwritten by proj_k

  embed_k<<<(BT * CC) / 256, 256, 0, stream>>>(emb, tokens, X);

  const dim3 gQKV(1, BT / BM);             // N=64
  const dim3 gC(CC / BN, BT / BM);         // N=256
  const dim3 gP((2 * OUTD) / BN, BT / BM); // N=384

  for (int l = 0; l < LL; ++l) {
    const float* Wq_l = Wq + (size_t)l * CC * CC;
    const float* Wk_l = Wk + (size_t)l * CC * CC;
    const float* Wv_l = Wv + (size_t)l * CC * CC;
    const float* Wo_l = Wo + (size_t)l * CC * CC;
    const float* bq_l = bq + (size_t)l * CC;
    const float* bk_l = bk + (size_t)l * CC;
    const float* bv_l = bv + (size_t)l * CC;
    const float* bo_l = bo + (size_t)l * CC;
    const float* rk_l = relk + (size_t)l * (2 * WSZ + 1) * HD;
    const float* rv_l = relv + (size_t)l * (2 * WSZ + 1) * HD;

    for (int h = 0; h < HH; ++h) {
      gemm_k<float, u16><<<gQKV, 256, 0, stream>>>(X, Wq_l + h * HD, CC, bq_l + h * HD,
                                                   Qh, HD, CC, 0.125f, 0, 0);
      gemm_k<float, u16><<<gQKV, 256, 0, stream>>>(X, Wk_l + h * HD, CC, bk_l + h * HD,
                                                   Kh, HD, CC, 1.0f, 0, 0);
      gemm_k<float, u16><<<gQKV, 256, 0, stream>>>(X, Wv_l + h * HD, CC, bv_l + h * HD,
                                                   Vh, HD, CC, 1.0f, 0, 0);
      attn_k<<<BB * TT, 256, 0, stream>>>(Qh, Kh, Vh, rk_l, rv_l, xlen, Ob, h * HD);
    }
    gemm_k<float, float><<<gC, 256, 0, stream>>>(Ob, Wo_l, CC, bo_l, T5, CC,
                                                 CC, 1.0f, 0, 0);
    addln_k<<<BT, 256, 0, stream>>>(X, T5, ln1g + (size_t)l * CC,
                                    ln1b + (size_t)l * CC, xlen, 0);
    for (int c = 0; c < 4; ++c) {
      gemm_k<float, u16><<<gC, 256, 0, stream>>>(X, W1 + (size_t)l * CC * FCD + c * 256,
                                                 FCD, b1 + (size_t)l * FCD + c * 256,
                                                 Hc, 256, CC, 1.0f, 1, 0);
      gemm_k<u16, float><<<gC, 256, 0, stream>>>(Hc,
                                                 W2 + (size_t)l * FCD * CC + (size_t)c * 256 * CC,
                                                 CC, (c == 0) ? (b2 + (size_t)l * CC) : nullptr,
                                                 T5, CC, 256, 1.0f, 0, (c > 0));
    }
    addln_k<<<BT, 256, 0, stream>>>(X, T5, ln2g + (size_t)l * CC,
                                    ln2b + (size_t)l * CC, xlen, 1);
  }

  proj_k<<<gP, 256, 0, stream>>>(X, projw, projb, xlen, out);
  pack_xbct_k<<<(BB * CC * TT) / 256, 256, 0, stream>>>(X, out);
  pack_mask_k<<<(BB * TT) / 256, 256, 0, stream>>>(xlen, out);
}

// Round 11
// 4897.190 us; speedup vs baseline: 2.0923x; 2.0923x over previous
//
#include <hip/hip_runtime.h>

typedef unsigned short u16;

// Problem constants
#define CC   256
#define HH   4
#define HD   64
#define LL   6
#define FCD  1024
#define OUTD 192
#define WSZ  4
#define BB   8
#define TT   1024
#define BT   8192   // B*T

// Output flat offsets (fp32 elements)
#define OFF_XBCT 0
#define OFF_M    2097152
#define OFF_LOGS 3670016
#define OFF_MASK 5242880

__device__ __forceinline__ float bf2f(u16 u) {
  union { unsigned int i; float f; } v; v.i = ((unsigned int)u) << 16; return v.f;
}
__device__ __forceinline__ u16 f2bf(float f) {
  union { float f; unsigned int i; } v; v.f = f;
  unsigned int x = v.i;
  return (u16)((x + 0x7fffu + ((x >> 16) & 1u)) >> 16);
}
__device__ __forceinline__ void ldv4(const float* p, float* o) {
  float4 v = *reinterpret_cast<const float4*>(p);
  o[0] = v.x; o[1] = v.y; o[2] = v.z; o[3] = v.w;
}
__device__ __forceinline__ void ldv4(const u16* p, float* o) {
  ushort4 v = *reinterpret_cast<const ushort4*>(p);
  o[0] = bf2f(v.x); o[1] = bf2f(v.y); o[2] = bf2f(v.z); o[3] = bf2f(v.w);
}
__device__ __forceinline__ float ld_e(const float* p) { return *p; }
__device__ __forceinline__ float ld_e(const u16* p)   { return bf2f(*p); }
__device__ __forceinline__ void st_e(float* p, float v) { *p = v; }
__device__ __forceinline__ void st_e(u16* p, float v)   { *p = f2bf(v); }

// ---------------- Embedding ----------------
__global__ __launch_bounds__(256) void embed_k(
    const float* __restrict__ emb, const int* __restrict__ tokens,
    float* __restrict__ X)
{
  const int i = blockIdx.x * 256 + threadIdx.x;   // BT*CC
  const int bt = i >> 8;
  const int c  = i & (CC - 1);
  X[i] = emb[(size_t)tokens[bt] * CC + c] * 16.0f;
}

// ---------------- Tiled GEMM (verified core) ----------------
#define BM 64
#define BN 64
#define BK 16
template <typename AT, typename CT>
__global__ __launch_bounds__(256) void gemm_k(
    const AT* __restrict__ A, const float* __restrict__ W, int ldb,
    const float* __restrict__ bias, CT* __restrict__ C, int ldc,
    int K, float ps, int relu, int accum)
{
  __shared__ float As[BK][BM + 1];
  __shared__ float Bs[BK][BN + 1];
  const int tid = threadIdx.x;
  const int bm = blockIdx.y * BM;
  const int bn = blockIdx.x * BN;
  const int tr = (tid >> 4) << 2;
  const int tc = (tid & 15) << 2;
  const int ar = tid >> 2;
  const int ac = (tid & 3) << 2;
  float acc[4][4] = {{0.0f}};
  float tmp[4];
  for (int k0 = 0; k0 < K; k0 += BK) {
    ldv4(A + (size_t)(bm + ar) * K + (k0 + ac), tmp);
    As[ac + 0][ar] = tmp[0]; As[ac + 1][ar] = tmp[1];
    As[ac + 2][ar] = tmp[2]; As[ac + 3][ar] = tmp[3];
    const int rk = tid >> 4;
    const int cn = (tid & 15) << 2;
    ldv4(W + (size_t)(k0 + rk) * ldb + (bn + cn), tmp);
    Bs[rk][cn + 0] = tmp[0]; Bs[rk][cn + 1] = tmp[1];
    Bs[rk][cn + 2] = tmp[2]; Bs[rk][cn + 3] = tmp[3];
    __syncthreads();
#pragma unroll
    for (int kk = 0; kk < BK; ++kk) {
      const float a0 = As[kk][tr + 0], a1 = As[kk][tr + 1];
      const float a2 = As[kk][tr + 2], a3 = As[kk][tr + 3];
      const float b0 = Bs[kk][tc + 0], b1 = Bs[kk][tc + 1];
      const float b2 = Bs[kk][tc + 2], b3 = Bs[kk][tc + 3];
      acc[0][0] += a0 * b0; acc[0][1] += a0 * b1; acc[0][2] += a0 * b2; acc[0][3] += a0 * b3;
      acc[1][0] += a1 * b0; acc[1][1] += a1 * b1; acc[1][2] += a1 * b2; acc[1][3] += a1 * b3;
      acc[2][0] += a2 * b0; acc[2][1] += a2 * b1; acc[2][2] += a2 * b2; acc[2][3] += a2 * b3;
      acc[3][0] += a3 * b0; acc[3][1] += a3 * b1; acc[3][2] += a3 * b2; acc[3][3] += a3 * b3;
    }
    __syncthreads();
  }
#pragma unroll
  for (int i = 0; i < 4; ++i) {
    const size_t row = (size_t)(bm + tr + i);
#pragma unroll
    for (int j = 0; j < 4; ++j) {
      const int col = bn + tc + j;
      float vv = acc[i][j];
      if (bias) vv += bias[col];
      vv *= ps;
      if (relu) vv = fmaxf(vv, 0.0f);
      const size_t ci = row * ldc + col;
      if (accum) vv += ld_e(C + ci);
      st_e(C + ci, vv);
    }
  }
}

// ---------------- Flash attention: block = (qtile 64, b, h) ----------------
// Qb/Kb/Vb: BT x 256 bf16 (all heads; Q pre-scaled 0.125). rk/rv: fp32 9x64.
// Ob: BT x 256 fp32, block writes 64-col head slice.
__global__ __launch_bounds__(256) void fattn_k(
    const u16* __restrict__ Qb, const u16* __restrict__ Kb,
    const u16* __restrict__ Vb, const float* __restrict__ rk,
    const float* __restrict__ rv, const int* __restrict__ xlen,
    float* __restrict__ Ob)
{
  __shared__ u16  Ql[64][72];
  __shared__ u16  Kl[64][72];
  __shared__ u16  Vl[64][72];
  __shared__ float Sb[64][68];
  __shared__ float rkl[9][64];
  __shared__ float rvl[9][68];
  __shared__ float qrel[64][9];
  __shared__ float mrow[64], lrow[64], arow[64];
  __shared__ float pmax[64][4], psum[64][4];

  const int qt = blockIdx.x;          // 0..15
  const int bh = blockIdx.y;          // b*4 + h
  const int b  = bh >> 2;
  const int h  = bh & 3;
  const int tid = threadIdx.x;
  const int len = xlen[b];
  const int q0  = qt << 6;

  for (int i = tid; i < 9 * 64; i += 256) {
    rkl[i >> 6][i & 63] = rk[i];
    rvl[i >> 6][i & 63] = rv[i];
  }
  for (int i = tid; i < 64 * 16; i += 256) {
    const int r = i >> 4, c4 = (i & 15) << 2;
    ushort4 v = *reinterpret_cast<const ushort4*>(
        Qb + (size_t)((b << 10) + q0 + r) * CC + (h << 6) + c4);
    Ql[r][c4] = v.x; Ql[r][c4 + 1] = v.y; Ql[r][c4 + 2] = v.z; Ql[r][c4 + 3] = v.w;
  }
  if (tid < 64) { mrow[tid] = -3.0e38f; lrow[tid] = 0.0f; }
  __syncthreads();
  for (int i = tid; i < 64 * 9; i += 256) {
    const int r = i / 9, j = i - r * 9;
    float s = 0.0f;
#pragma unroll 16
    for (int d = 0; d < 64; ++d) s += bf2f(Ql[r][d]) * rkl[j][d];
    qrel[r][j] = s;
  }
  __syncthreads();

  const int tq = (tid >> 4) << 2;
  const int tk = (tid & 15) << 2;
  float O[4][4] = {{0.0f}};

  for (int kt = 0; kt < 16; ++kt) {
    const int k0 = kt << 6;
    for (int i = tid; i < 64 * 16; i += 256) {
      const int r = i >> 4, c4 = (i & 15) << 2;
      const size_t g = (size_t)((b << 10) + k0 + r) * CC + (h << 6) + c4;
      ushort4 kv = *reinterpret_cast<const ushort4*>(Kb + g);
      Kl[r][c4] = kv.x; Kl[r][c4 + 1] = kv.y; Kl[r][c4 + 2] = kv.z; Kl[r][c4 + 3] = kv.w;
      ushort4 vv = *reinterpret_cast<const ushort4*>(Vb + g);
      Vl[r][c4] = vv.x; Vl[r][c4 + 1] = vv.y; Vl[r][c4 + 2] = vv.z; Vl[r][c4 + 3] = vv.w;
    }
    __syncthreads();

    float S[4][4] = {{0.0f}};
    for (int d = 0; d < 64; d += 4) {
      float qv[4][4], kv[4][4];
#pragma unroll
      for (int i = 0; i < 4; ++i) {
        ushort4 t = *reinterpret_cast<const ushort4*>(&Ql[tq + i][d]);
        qv[i][0] = bf2f(t.x); qv[i][1] = bf2f(t.y);
        qv[i][2] = bf2f(t.z); qv[i][3] = bf2f(t.w);
        ushort4 u = *reinterpret_cast<const ushort4*>(&Kl[tk + i][d]);
        kv[i][0] = bf2f(u.x); kv[i][1] = bf2f(u.y);
        kv[i][2] = bf2f(u.z); kv[i][3] = bf2f(u.w);
      }
#pragma unroll
      for (int i = 0; i < 4; ++i)
#pragma unroll
        for (int j = 0; j < 4; ++j)
          S[i][j] += qv[i][0] * kv[j][0] + qv[i][1] * kv[j][1]
                   + qv[i][2] * kv[j][2] + qv[i][3] * kv[j][3];
    }
#pragma unroll
    for (int i = 0; i < 4; ++i) {
      const int q = q0 + tq + i;
#pragma unroll
      for (int j = 0; j < 4; ++j) {
        const int k = k0 + tk + j;
        float s = S[i][j];
        const int r = k - q;
        if (r >= -WSZ && r <= WSZ) s += qrel[tq + i][r + WSZ];
        if (q >= len || k >= len) s = -10000.0f;
        Sb[tq + i][tk + j] = s;
      }
    }
    __syncthreads();
    {
      const int row = tid & 63, seg = tid >> 6;
      float m = -3.0e38f;
      for (int c = seg * 16; c < seg * 16 + 16; ++c) m = fmaxf(m, Sb[row][c]);
      pmax[row][seg] = m;
    }
    __syncthreads();
    if (tid < 64) {
      const float mo = mrow[tid];
      float mn = fmaxf(fmaxf(pmax[tid][0], pmax[tid][1]),
                       fmaxf(pmax[tid][2], pmax[tid][3]));
      mn = fmaxf(mo, mn);
      const float a = __expf(mo - mn);
      mrow[tid] = mn; arow[tid] = a;
      lrow[tid] *= a;
    }
    __syncthreads();
    {
      const int row = tid & 63, seg = tid >> 6;
      const float mn = mrow[row];
      float s = 0.0f;
      for (int c = seg * 16; c < seg * 16 + 16; ++c) {
        const float p = __expf(Sb[row][c] - mn);
        Sb[row][c] = p; s += p;
      }
      psum[row][seg] = s;
    }
    __syncthreads();
    if (tid < 64)
      lrow[tid] += psum[tid][0] + psum[tid][1] + psum[tid][2] + psum[tid][3];

#pragma unroll
    for (int i = 0; i < 4; ++i) {
      const float a = arow[tq + i];
      O[i][0] *= a; O[i][1] *= a; O[i][2] *= a; O[i][3] *= a;
    }
    for (int kk = 0; kk < 64; kk += 4) {
      float pv[4][4], vv[4][4];
#pragma unroll
      for (int i = 0; i < 4; ++i) {
        float4 t = *reinterpret_cast<const float4*>(&Sb[tq + i][kk]);
        pv[i][0] = t.x; pv[i][1] = t.y; pv[i][2] = t.z; pv[i][3] = t.w;
        ushort4 u = *reinterpret_cast<const ushort4*>(&Vl[kk + i][tk]);
        vv[i][0] = bf2f(u.x); vv[i][1] = bf2f(u.y);
        vv[i][2] = bf2f(u.z); vv[i][3] = bf2f(u.w);
      }
#pragma unroll
      for (int i = 0; i < 4; ++i)
#pragma unroll
        for (int j = 0; j < 4; ++j)
          O[i][j] += pv[i][0] * vv[0][j] + pv[i][1] * vv[1][j]
                   + pv[i][2] * vv[2][j] + pv[i][3] * vv[3][j];
    }
    // rel_v band (p values still in Sb, same rescaling as O)
#pragma unroll
    for (int i = 0; i < 4; ++i) {
      const int q = q0 + tq + i;
#pragma unroll
      for (int r = -WSZ; r <= WSZ; ++r) {
        const int k = q + r;
        if (k >= k0 && k < k0 + 64) {
          const float p = Sb[tq + i][k - k0];
          O[i][0] += p * rvl[r + WSZ][tk + 0];
          O[i][1] += p * rvl[r + WSZ][tk + 1];
          O[i][2] += p * rvl[r + WSZ][tk + 2];
          O[i][3] += p * rvl[r + WSZ][tk + 3];
        }
      }
    }
    __syncthreads();
  }

#pragma unroll
  for (int i = 0; i < 4; ++i) {
    const float inv = 1.0f / lrow[tq + i];
    float4 o;
    o.x = O[i][0] * inv; o.y = O[i][1] * inv;
    o.z = O[i][2] * inv; o.w = O[i][3] * inv;
    *reinterpret_cast<float4*>(
        Ob + (size_t)((b << 10) + q0 + tq + i) * CC + (h << 6) + tk) = o;
  }
}

// ---------------- Residual add + LayerNorm ----------------
__global__ __launch_bounds__(256) void addln_k(
    float* __restrict__ X, const float* __restrict__ R,
    const float* __restrict__ g, const float* __restrict__ be,
    const int* __restrict__ xlen, int am)
{
  __shared__ float red[256];
  const int row = blockIdx.x;
  const int tid = threadIdx.x;
  const int b = row >> 10;
  const int t = row & (TT - 1);
  const size_t base = (size_t)row * CC;
  const float v = X[base + tid] + R[base + tid];
  red[tid] = v; __syncthreads();
  for (int s2 = 128; s2 > 0; s2 >>= 1) {
    if (tid < s2) red[tid] += red[tid + s2];
    __syncthreads();
  }
  const float mean = red[0] * (1.0f / CC);
  __syncthreads();
  const float dv = v - mean;
  red[tid] = dv * dv; __syncthreads();
  for (int s2 = 128; s2 > 0; s2 >>= 1) {
    if (tid < s2) red[tid] += red[tid + s2];
    __syncthreads();
  }
  const float var = red[0] * (1.0f / CC);
  float y = dv * rsqrtf(var + 1e-5f) * g[tid] + be[tid];
  if (am && t >= xlen[b]) y = 0.0f;
  X[base + tid] = y;
}

// ---------------- Final projection -> fp32 m/logs, masked ----------------
__global__ __launch_bounds__(256) void proj_k(
    const float* __restrict__ A, const float* __restrict__ W,
    const float* __restrict__ bias, const int* __restrict__ xlen,
    float* __restrict__ out)
{
  __shared__ float As[BK][BM + 1];
  __shared__ float Bs[BK][BN + 1];
  const int tid = threadIdx.x;
  const int bm = blockIdx.y * BM;
  const int bn = blockIdx.x * BN;
  const int tr = (tid >> 4) << 2;
  const int tc = (tid & 15) << 2;
  const int ar = tid >> 2;
  const int ac = (tid & 3) << 2;
  float acc[4][4] = {{0.0f}};
  float tmp[4];
  for (int k0 = 0; k0 < CC; k0 += BK) {
    ldv4(A + (size_t)(bm + ar) * CC + (k0 + ac), tmp);
    As[ac + 0][ar] = tmp[0]; As[ac + 1][ar] = tmp[1];
    As[ac + 2][ar] = tmp[2]; As[ac + 3][ar] = tmp[3];
    const int nn = tid >> 2;
    const int kx = (tid & 3) << 2;
    ldv4(W + (size_t)(bn + nn) * CC + (k0 + kx), tmp);
    Bs[kx + 0][nn] = tmp[0]; Bs[kx + 1][nn] = tmp[1];
    Bs[kx + 2][nn] = tmp[2]; Bs[kx + 3][nn] = tmp[3];
    __syncthreads();
#pragma unroll
    for (int kk = 0; kk < BK; ++kk) {
      const float a0 = As[kk][tr + 0], a1 = As[kk][tr + 1];
      const float a2 = As[kk][tr + 2], a3 = As[kk][tr + 3];
      const float b0 = Bs[kk][tc + 0], b1 = Bs[kk][tc + 1];
      const float b2 = Bs[kk][tc + 2], b3 = Bs[kk][tc + 3];
      acc[0][0] += a0 * b0; acc[0][1] += a0 * b1; acc[0][2] += a0 * b2; acc[0][3] += a0 * b3;
      acc[1][0] += a1 * b0; acc[1][1] += a1 * b1; acc[1][2] += a1 * b2; acc[1][3] += a1 * b3;
      acc[2][0] += a2 * b0; acc[2][1] += a2 * b1; acc[2][2] += a2 * b2; acc[2][3] += a2 * b3;
      acc[3][0] += a3 * b0; acc[3][1] += a3 * b1; acc[3][2] += a3 * b2; acc[3][3] += a3 * b3;
    }
    __syncthreads();
  }
#pragma unroll
  for (int i = 0; i < 4; ++i) {
    const int row = bm + tr + i;
    const int b = row >> 10;
    const int t = row & (TT - 1);
    const int len = xlen[b];
#pragma unroll
    for (int j = 0; j < 4; ++j) {
      const int o = bn + tc + j;
      float vv = acc[i][j] + bias[o];
      if (t >= len) vv = 0.0f;
      const size_t dst = (o < OUTD)
          ? (size_t)OFF_M    + ((size_t)b * OUTD + o) * TT + t
          : (size_t)OFF_LOGS + ((size_t)b * OUTD + (o - OUTD)) * TT + t;
      out[dst] = vv;
    }
  }
}

// ---------------- Output packing ----------------
__global__ __launch_bounds__(256) void pack_xbct_k(
    const float* __restrict__ X, float* __restrict__ out)
{
  const int i = blockIdx.x * 256 + threadIdx.x;
  const int b = i >> 18;
  const int c = (i >> 10) & (CC - 1);
  const int t = i & (TT - 1);
  out[OFF_XBCT + i] = X[((size_t)b << 18) + ((size_t)t << 8) + c];
}

__global__ __launch_bounds__(256) void pack_mask_k(
    const int* __restrict__ xlen, float* __restrict__ out)
{
  const int i = blockIdx.x * 256 + threadIdx.x;
  const int b = i >> 10;
  const int t = i & (TT - 1);
  out[OFF_MASK + i] = (t < xlen[b]) ? 1.0f : 0.0f;
}

extern "C" void kernel_launch(void* const* d_in, const int* in_sizes, int n_in,
                              void* d_out, int out_size, void* d_ws, size_t ws_size,
                              hipStream_t stream)
{
  (void)in_sizes; (void)n_in; (void)out_size; (void)ws_size;
  const float* emb   = (const float*)d_in[0];
  const float* Wq    = (const float*)d_in[1];
  const float* Wk    = (const float*)d_in[2];
  const float* Wv    = (const float*)d_in[3];
  const float* Wo    = (const float*)d_in[4];
  const float* bq    = (const float*)d_in[5];
  const float* bk    = (const float*)d_in[6];
  const float* bv    = (const float*)d_in[7];
  const float* bo    = (const float*)d_in[8];
  const float* relk  = (const float*)d_in[9];
  const float* relv  = (const float*)d_in[10];
  const float* ln1g  = (const float*)d_in[11];
  const float* ln1b  = (const float*)d_in[12];
  const float* ln2g  = (const float*)d_in[13];
  const float* ln2b  = (const float*)d_in[14];
  const float* W1    = (const float*)d_in[15];
  const float* b1    = (const float*)d_in[16];
  const float* W2    = (const float*)d_in[17];
  const float* b2    = (const float*)d_in[18];
  const float* projw = (const float*)d_in[19];
  const float* projb = (const float*)d_in[20];
  const int*   tokens = (const int*)d_in[21];
  const int*   xlen   = (const int*)d_in[22];
  float* out = (float*)d_out;

  // ws (12 MB): X fp32 (8MB) | pool 4MB (Qb bf16 BTx256, later FFN hidden chunk)
  float* X  = (float*)d_ws;
  u16* pool = (u16*)(X + (size_t)BT * CC);
  u16* Qb = pool;                            // BT x 256 bf16 (4MB)
  u16* Hc = pool;                            // FFN hidden chunk (aliases Qb, disjoint phase)
  // d_out scratch (dead before final writes):
  float* Ob = out + OFF_XBCT;                // BT x 256 fp32
  u16*   Kb = (u16*)(out + OFF_M);           // BT x 256 bf16 (4MB of M region)
  u16*   Vb = (u16*)(out + OFF_LOGS);        // BT x 256 bf16 (4MB of LOGS region)
  float* T5 = out + OFF_M;                   // BT x 256 fp32 (after K/V dead)

  embed_k<<<(BT * CC) / 256, 256, 0, stream>>>(emb, tokens, X);

  const dim3 gC(CC / BN, BT / BM);           // (4,128) N=256 GEMMs
  const dim3 gA(16, BB * HH);                // flash attn: 16 qtiles x 32 bh
  const dim3 gP((2 * OUTD) / BN, BT / BM);

  for (int l = 0; l < LL; ++l) {
    const float* Wq_l = Wq + (size_t)l * CC * CC;
    const float* Wk_l = Wk + (size_t)l * CC * CC;
    const float* Wv_l = Wv + (size_t)l * CC * CC;
    const float* Wo_l = Wo + (size_t)l * CC * CC;
    const float* rk_l = relk + (size_t)l * (2 * WSZ + 1) * HD;
    const float* rv_l = relv + (size_t)l * (2 * WSZ + 1) * HD;

    gemm_k<float, u16><<<gC, 256, 0, stream>>>(X, Wq_l, CC, bq + (size_t)l * CC,
                                               Qb, CC, CC, 0.125f, 0, 0);
    gemm_k<float, u16><<<gC, 256, 0, stream>>>(X, Wk_l, CC, bk + (size_t)l * CC,
                                               Kb, CC, CC, 1.0f, 0, 0);
    gemm_k<float, u16><<<gC, 256, 0, stream>>>(X, Wv_l, CC, bv + (size_t)l * CC,
                                               Vb, CC, CC, 1.0f, 0, 0);
    fattn_k<<<gA, 256, 0, stream>>>(Qb, Kb, Vb, rk_l, rv_l, xlen, Ob);
    gemm_k<float, float><<<gC, 256, 0, stream>>>(Ob, Wo_l, CC, bo + (size_t)l * CC,
                                                 T5, CC, CC, 1.0f, 0, 0);
    addln_k<<<BT, 256, 0, stream>>>(X, T5, ln1g + (size_t)l * CC,
                                    ln1b + (size_t)l * CC, xlen, 0);
    for (int c = 0; c < 4; ++c) {
      gemm_k<float, u16><<<gC, 256, 0, stream>>>(X, W1 + (size_t)l * CC * FCD + c * 256,
                                                 FCD, b1 + (size_t)l * FCD + c * 256,
                                                 Hc, 256, CC, 1.0f, 1, 0);
      gemm_k<u16, float><<<gC, 256, 0, stream>>>(Hc,
                                                 W2 + (size_t)l * FCD * CC + (size_t)c * 256 * CC,
                                                 CC, (c == 0) ? (b2 + (size_t)l * CC) : nullptr,
                                                 T5, CC, 256, 1.0f, 0, (c > 0));
    }
    addln_k<<<BT, 256, 0, stream>>>(X, T5, ln2g + (size_t)l * CC,
                                    ln2b + (size_t)l * CC, xlen, 1);
  }

  proj_k<<<gP, 256, 0, stream>>>(X, projw, projb, xlen, out);
  pack_xbct_k<<<(BB * CC * TT) / 256, 256, 0, stream>>>(X, out);
  pack_mask_k<<<(BB * TT) / 256, 256, 0, stream>>>(xlen, out);
}

// Round 12
// 3873.238 us; speedup vs baseline: 2.6454x; 1.2644x over previous
//
#include <hip/hip_runtime.h>

typedef unsigned short u16;
typedef __attribute__((ext_vector_type(8))) short bf16x8;
typedef __attribute__((ext_vector_type(4))) float f32x4;

// Problem constants
#define CC   256
#define HH   4
#define HD   64
#define LL   6
#define FCD  1024
#define OUTD 192
#define WSZ  4
#define BB   8
#define TT   1024
#define BT   8192   // B*T

// Output flat offsets (fp32 elements)
#define OFF_XBCT 0
#define OFF_M    2097152
#define OFF_LOGS 3670016
#define OFF_MASK 5242880

__device__ __forceinline__ float bf2f(u16 u) {
  union { unsigned int i; float f; } v; v.i = ((unsigned int)u) << 16; return v.f;
}
__device__ __forceinline__ u16 f2bf(float f) {
  union { float f; unsigned int i; } v; v.f = f;
  unsigned int x = v.i;
  return (u16)((x + 0x7fffu + ((x >> 16) & 1u)) >> 16);
}
__device__ __forceinline__ void ldv4(const float* p, float* o) {
  float4 v = *reinterpret_cast<const float4*>(p);
  o[0] = v.x; o[1] = v.y; o[2] = v.z; o[3] = v.w;
}
__device__ __forceinline__ float ld_e(const float* p) { return *p; }
__device__ __forceinline__ float ld_e(const u16* p)   { return bf2f(*p); }
__device__ __forceinline__ void st_e(float* p, float v) { *p = v; }
__device__ __forceinline__ void st_e(u16* p, float v)   { *p = f2bf(v); }

// stage 8 contiguous elems of A as bf16 into d[0..7]
__device__ __forceinline__ void stage8(const float* p, u16* d) {
  float4 a = *reinterpret_cast<const float4*>(p);
  float4 b = *reinterpret_cast<const float4*>(p + 4);
  d[0] = f2bf(a.x); d[1] = f2bf(a.y); d[2] = f2bf(a.z); d[3] = f2bf(a.w);
  d[4] = f2bf(b.x); d[5] = f2bf(b.y); d[6] = f2bf(b.z); d[7] = f2bf(b.w);
}
__device__ __forceinline__ void stage8(const u16* p, u16* d) {
  ushort4 a = *reinterpret_cast<const ushort4*>(p);
  ushort4 b = *reinterpret_cast<const ushort4*>(p + 4);
  d[0] = a.x; d[1] = a.y; d[2] = a.z; d[3] = a.w;
  d[4] = b.x; d[5] = b.y; d[6] = b.z; d[7] = b.w;
}

// ---------------- Embedding ----------------
__global__ __launch_bounds__(256) void embed_k(
    const float* __restrict__ emb, const int* __restrict__ tokens,
    float* __restrict__ X)
{
  const int i = blockIdx.x * 256 + threadIdx.x;   // BT*CC
  const int bt = i >> 8;
  const int c  = i & (CC - 1);
  X[i] = emb[(size_t)tokens[bt] * CC + c] * 16.0f;
}

// ---------------- MFMA GEMM: C = ps*(A @ W [+ bias]), opt relu/accum ----------------
// A: M x K row-major (lda == K), fp32 or bf16 (converted to bf16 in staging).
// W: fp32 K x ldb row-major (pre-offset to column origin). K must be mult of 32.
// Tile 64x64, BK=32, 4 waves; wave w computes rows [16w,16w+16) x 64 cols via
// 4x mfma_f32_16x16x32_bf16. Frag layouts: A[m=lane&15][k=(lane>>4)*8+j],
// B[n=lane&15][k=(lane>>4)*8+j], C col=lane&15 row=(lane>>4)*4+reg (m89/m91).
template <typename AT, typename CT>
__global__ __launch_bounds__(256) void gemm_m_k(
    const AT* __restrict__ A, const float* __restrict__ W, int ldb,
    const float* __restrict__ bias, CT* __restrict__ C, int ldc,
    int K, float ps, int relu, int accum)
{
  __shared__ u16 As[64][40];   // [m][k], +8 pad (16B-aligned rows)
  __shared__ u16 Bs[64][40];   // [n][k]
  const int tid  = threadIdx.x;
  const int lane = tid & 63;
  const int wv   = tid >> 6;
  const int bm = blockIdx.y * 64;
  const int bn = blockIdx.x * 64;
  const int l15 = lane & 15;
  const int lq  = lane >> 4;          // 0..3
  // staging maps
  const int ar = tid >> 2;            // A row 0..63
  const int ak = (tid & 3) << 3;      // A k-offset 0,8,16,24
  const int kr = tid & 31;            // B k-row 0..31
  const int nb = (tid >> 5) << 3;     // B n-group 0,8,..,56

  f32x4 acc[4];
#pragma unroll
  for (int nt = 0; nt < 4; ++nt) acc[nt] = (f32x4){0.0f, 0.0f, 0.0f, 0.0f};

  for (int k0 = 0; k0 < K; k0 += 32) {
    u16 t8[8];
    stage8(A + (size_t)(bm + ar) * K + (k0 + ak), t8);
    *reinterpret_cast<ushort4*>(&As[ar][ak]) =
        make_ushort4(t8[0], t8[1], t8[2], t8[3]);
    *reinterpret_cast<ushort4*>(&As[ar][ak + 4]) =
        make_ushort4(t8[4], t8[5], t8[6], t8[7]);
    float w8[8];
    ldv4(W + (size_t)(k0 + kr) * ldb + (bn + nb), w8);
    ldv4(W + (size_t)(k0 + kr) * ldb + (bn + nb + 4), w8 + 4);
#pragma unroll
    for (int j = 0; j < 8; ++j) Bs[nb + j][kr] = f2bf(w8[j]);
    __syncthreads();

    const bf16x8 af = *reinterpret_cast<const bf16x8*>(&As[(wv << 4) + l15][lq << 3]);
#pragma unroll
    for (int nt = 0; nt < 4; ++nt) {
      const bf16x8 bf = *reinterpret_cast<const bf16x8*>(&Bs[(nt << 4) + l15][lq << 3]);
      acc[nt] = __builtin_amdgcn_mfma_f32_16x16x32_bf16(af, bf, acc[nt], 0, 0, 0);
    }
    __syncthreads();
  }

#pragma unroll
  for (int nt = 0; nt < 4; ++nt) {
#pragma unroll
    for (int r = 0; r < 4; ++r) {
      const int row = bm + (wv << 4) + (lq << 2) + r;
      const int col = bn + (nt << 4) + l15;
      float vv = acc[nt][r];
      if (bias) vv += bias[col];
      vv *= ps;
      if (relu) vv = fmaxf(vv, 0.0f);
      const size_t ci = (size_t)row * ldc + col;
      if (accum) vv += ld_e(C + ci);
      st_e(C + ci, vv);
    }
  }
}

// ---------------- Flash attention: block = (qtile 64, b, h) ----------------
__global__ __launch_bounds__(256) void fattn_k(
    const u16* __restrict__ Qb, const u16* __restrict__ Kb,
    const u16* __restrict__ Vb, const float* __restrict__ rk,
    const float* __restrict__ rv, const int* __restrict__ xlen,
    float* __restrict__ Ob)
{
  __shared__ u16  Ql[64][72];
  __shared__ u16  Kl[64][72];
  __shared__ u16  Vl[64][72];
  __shared__ float Sb[64][68];
  __shared__ float rkl[9][64];
  __shared__ float rvl[9][68];
  __shared__ float qrel[64][9];
  __shared__ float mrow[64], lrow[64], arow[64];
  __shared__ float pmax[64][4], psum[64][4];

  const int qt = blockIdx.x;
  const int bh = blockIdx.y;
  const int b  = bh >> 2;
  const int h  = bh & 3;
  const int tid = threadIdx.x;
  const int len = xlen[b];
  const int q0  = qt << 6;

  for (int i = tid; i < 9 * 64; i += 256) {
    rkl[i >> 6][i & 63] = rk[i];
    rvl[i >> 6][i & 63] = rv[i];
  }
  for (int i = tid; i < 64 * 16; i += 256) {
    const int r = i >> 4, c4 = (i & 15) << 2;
    ushort4 v = *reinterpret_cast<const ushort4*>(
        Qb + (size_t)((b << 10) + q0 + r) * CC + (h << 6) + c4);
    Ql[r][c4] = v.x; Ql[r][c4 + 1] = v.y; Ql[r][c4 + 2] = v.z; Ql[r][c4 + 3] = v.w;
  }
  if (tid < 64) { mrow[tid] = -3.0e38f; lrow[tid] = 0.0f; }
  __syncthreads();
  for (int i = tid; i < 64 * 9; i += 256) {
    const int r = i / 9, j = i - r * 9;
    float s = 0.0f;
#pragma unroll 16
    for (int d = 0; d < 64; ++d) s += bf2f(Ql[r][d]) * rkl[j][d];
    qrel[r][j] = s;
  }
  __syncthreads();

  const int tq = (tid >> 4) << 2;
  const int tk = (tid & 15) << 2;
  float O[4][4] = {{0.0f}};

  for (int kt = 0; kt < 16; ++kt) {
    const int k0 = kt << 6;
    for (int i = tid; i < 64 * 16; i += 256) {
      const int r = i >> 4, c4 = (i & 15) << 2;
      const size_t g = (size_t)((b << 10) + k0 + r) * CC + (h << 6) + c4;
      ushort4 kv = *reinterpret_cast<const ushort4*>(Kb + g);
      Kl[r][c4] = kv.x; Kl[r][c4 + 1] = kv.y; Kl[r][c4 + 2] = kv.z; Kl[r][c4 + 3] = kv.w;
      ushort4 vv = *reinterpret_cast<const ushort4*>(Vb + g);
      Vl[r][c4] = vv.x; Vl[r][c4 + 1] = vv.y; Vl[r][c4 + 2] = vv.z; Vl[r][c4 + 3] = vv.w;
    }
    __syncthreads();

    float S[4][4] = {{0.0f}};
    for (int d = 0; d < 64; d += 4) {
      float qv[4][4], kv[4][4];
#pragma unroll
      for (int i = 0; i < 4; ++i) {
        ushort4 t = *reinterpret_cast<const ushort4*>(&Ql[tq + i][d]);
        qv[i][0] = bf2f(t.x); qv[i][1] = bf2f(t.y);
        qv[i][2] = bf2f(t.z); qv[i][3] = bf2f(t.w);
        ushort4 u = *reinterpret_cast<const ushort4*>(&Kl[tk + i][d]);
        kv[i][0] = bf2f(u.x); kv[i][1] = bf2f(u.y);
        kv[i][2] = bf2f(u.z); kv[i][3] = bf2f(u.w);
      }
#pragma unroll
      for (int i = 0; i < 4; ++i)
#pragma unroll
        for (int j = 0; j < 4; ++j)
          S[i][j] += qv[i][0] * kv[j][0] + qv[i][1] * kv[j][1]
                   + qv[i][2] * kv[j][2] + qv[i][3] * kv[j][3];
    }
#pragma unroll
    for (int i = 0; i < 4; ++i) {
      const int q = q0 + tq + i;
#pragma unroll
      for (int j = 0; j < 4; ++j) {
        const int k = k0 + tk + j;
        float s = S[i][j];
        const int r = k - q;
        if (r >= -WSZ && r <= WSZ) s += qrel[tq + i][r + WSZ];
        if (q >= len || k >= len) s = -10000.0f;
        Sb[tq + i][tk + j] = s;
      }
    }
    __syncthreads();
    {
      const int row = tid >> 2, seg = tid & 3;   // remapped: <=4-way conflicts
      float m = -3.0e38f;
      for (int c = seg * 16; c < seg * 16 + 16; ++c) m = fmaxf(m, Sb[row][c]);
      pmax[row][seg] = m;
    }
    __syncthreads();
    if (tid < 64) {
      const float mo = mrow[tid];
      float mn = fmaxf(fmaxf(pmax[tid][0], pmax[tid][1]),
                       fmaxf(pmax[tid][2], pmax[tid][3]));
      mn = fmaxf(mo, mn);
      const float a = __expf(mo - mn);
      mrow[tid] = mn; arow[tid] = a;
      lrow[tid] *= a;
    }
    __syncthreads();
    {
      const int row = tid >> 2, seg = tid & 3;   // remapped
      const float mn = mrow[row];
      float s = 0.0f;
      for (int c = seg * 16; c < seg * 16 + 16; ++c) {
        const float p = __expf(Sb[row][c] - mn);
        Sb[row][c] = p; s += p;
      }
      psum[row][seg] = s;
    }
    __syncthreads();
    if (tid < 64)
      lrow[tid] += psum[tid][0] + psum[tid][1] + psum[tid][2] + psum[tid][3];

#pragma unroll
    for (int i = 0; i < 4; ++i) {
      const float a = arow[tq + i];
      O[i][0] *= a; O[i][1] *= a; O[i][2] *= a; O[i][3] *= a;
    }
    for (int kk = 0; kk < 64; kk += 4) {
      float pv[4][4], vv[4][4];
#pragma unroll
      for (int i = 0; i < 4; ++i) {
        float4 t = *reinterpret_cast<const float4*>(&Sb[tq + i][kk]);
        pv[i][0] = t.x; pv[i][1] = t.y; pv[i][2] = t.z; pv[i][3] = t.w;
        ushort4 u = *reinterpret_cast<const ushort4*>(&Vl[kk + i][tk]);
        vv[i][0] = bf2f(u.x); vv[i][1] = bf2f(u.y);
        vv[i][2] = bf2f(u.z); vv[i][3] = bf2f(u.w);
      }
#pragma unroll
      for (int i = 0; i < 4; ++i)
#pragma unroll
        for (int j = 0; j < 4; ++j)
          O[i][j] += pv[i][0] * vv[0][j] + pv[i][1] * vv[1][j]
                   + pv[i][2] * vv[2][j] + pv[i][3] * vv[3][j];
    }
#pragma unroll
    for (int i = 0; i < 4; ++i) {
      const int q = q0 + tq + i;
#pragma unroll
      for (int r = -WSZ; r <= WSZ; ++r) {
        const int k = q + r;
        if (k >= k0 && k < k0 + 64) {
          const float p = Sb[tq + i][k - k0];
          O[i][0] += p * rvl[r + WSZ][tk + 0];
          O[i][1] += p * rvl[r + WSZ][tk + 1];
          O[i][2] += p * rvl[r + WSZ][tk + 2];
          O[i][3] += p * rvl[r + WSZ][tk + 3];
        }
      }
    }
    __syncthreads();
  }

#pragma unroll
  for (int i = 0; i < 4; ++i) {
    const float inv = 1.0f / lrow[tq + i];
    float4 o;
    o.x = O[i][0] * inv; o.y = O[i][1] * inv;
    o.z = O[i][2] * inv; o.w = O[i][3] * inv;
    *reinterpret_cast<float4*>(
        Ob + (size_t)((b << 10) + q0 + tq + i) * CC + (h << 6) + tk) = o;
  }
}

// ---------------- Residual add + LayerNorm ----------------
__global__ __launch_bounds__(256) void addln_k(
    float* __restrict__ X, const float* __restrict__ R,
    const float* __restrict__ g, const float* __restrict__ be,
    const int* __restrict__ xlen, int am)
{
  __shared__ float red[256];
  const int row = blockIdx.x;
  const int tid = threadIdx.x;
  const int b = row >> 10;
  const int t = row & (TT - 1);
  const size_t base = (size_t)row * CC;
  const float v = X[base + tid] + R[base + tid];
  red[tid] = v; __syncthreads();
  for (int s2 = 128; s2 > 0; s2 >>= 1) {
    if (tid < s2) red[tid] += red[tid + s2];
    __syncthreads();
  }
  const float mean = red[0] * (1.0f / CC);
  __syncthreads();
  const float dv = v - mean;
  red[tid] = dv * dv; __syncthreads();
  for (int s2 = 128; s2 > 0; s2 >>= 1) {
    if (tid < s2) red[tid] += red[tid + s2];
    __syncthreads();
  }
  const float var = red[0] * (1.0f / CC);
  float y = dv * rsqrtf(var + 1e-5f) * g[tid] + be[tid];
  if (am && t >= xlen[b]) y = 0.0f;
  X[base + tid] = y;
}

// ---------------- Final projection -> fp32 m/logs, masked (vector core) ----------------
#define BM 64
#define BN 64
#define BK 16
__global__ __launch_bounds__(256) void proj_k(
    const float* __restrict__ A, const float* __restrict__ W,
    const float* __restrict__ bias, const int* __restrict__ xlen,
    float* __restrict__ out)
{
  __shared__ float As[BK][BM + 1];
  __shared__ float Bs[BK][BN + 1];
  const int tid = threadIdx.x;
  const int bm = blockIdx.y * BM;
  const int bn = blockIdx.x * BN;
  const int tr = (tid >> 4) << 2;
  const int tc = (tid & 15) << 2;
  const int ar = tid >> 2;
  const int ac = (tid & 3) << 2;
  float acc[4][4] = {{0.0f}};
  float tmp[4];
  for (int k0 = 0; k0 < CC; k0 += BK) {
    ldv4(A + (size_t)(bm + ar) * CC + (k0 + ac), tmp);
    As[ac + 0][ar] = tmp[0]; As[ac + 1][ar] = tmp[1];
    As[ac + 2][ar] = tmp[2]; As[ac + 3][ar] = tmp[3];
    const int nn = tid >> 2;
    const int kx = (tid & 3) << 2;
    ldv4(W + (size_t)(bn + nn) * CC + (k0 + kx), tmp);
    Bs[kx + 0][nn] = tmp[0]; Bs[kx + 1][nn] = tmp[1];
    Bs[kx + 2][nn] = tmp[2]; Bs[kx + 3][nn] = tmp[3];
    __syncthreads();
#pragma unroll
    for (int kk = 0; kk < BK; ++kk) {
      const float a0 = As[kk][tr + 0], a1 = As[kk][tr + 1];
      const float a2 = As[kk][tr + 2], a3 = As[kk][tr + 3];
      const float b0 = Bs[kk][tc + 0], b1 = Bs[kk][tc + 1];
      const float b2 = Bs[kk][tc + 2], b3 = Bs[kk][tc + 3];
      acc[0][0] += a0 * b0; acc[0][1] += a0 * b1; acc[0][2] += a0 * b2; acc[0][3] += a0 * b3;
      acc[1][0] += a1 * b0; acc[1][1] += a1 * b1; acc[1][2] += a1 * b2; acc[1][3] += a1 * b3;
      acc[2][0] += a2 * b0; acc[2][1] += a2 * b1; acc[2][2] += a2 * b2; acc[2][3] += a2 * b3;
      acc[3][0] += a3 * b0; acc[3][1] += a3 * b1; acc[3][2] += a3 * b2; acc[3][3] += a3 * b3;
    }
    __syncthreads();
  }
#pragma unroll
  for (int i = 0; i < 4; ++i) {
    const int row = bm + tr + i;
    const int b = row >> 10;
    const int t = row & (TT - 1);
    const int len = xlen[b];
#pragma unroll
    for (int j = 0; j < 4; ++j) {
      const int o = bn + tc + j;
      float vv = acc[i][j] + bias[o];
      if (t >= len) vv = 0.0f;
      const size_t dst = (o < OUTD)
          ? (size_t)OFF_M    + ((size_t)b * OUTD + o) * TT + t
          : (size_t)OFF_LOGS + ((size_t)b * OUTD + (o - OUTD)) * TT + t;
      out[dst] = vv;
    }
  }
}

// ---------------- Output packing ----------------
__global__ __launch_bounds__(256) void pack_xbct_k(
    const float* __restrict__ X, float* __restrict__ out)
{
  const int i = blockIdx.x * 256 + threadIdx.x;
  const int b = i >> 18;
  const int c = (i >> 10) & (CC - 1);
  const int t = i & (TT - 1);
  out[OFF_XBCT + i] = X[((size_t)b << 18) + ((size_t)t << 8) + c];
}

__global__ __launch_bounds__(256) void pack_mask_k(
    const int* __restrict__ xlen, float* __restrict__ out)
{
  const int i = blockIdx.x * 256 + threadIdx.x;
  const int b = i >> 10;
  const int t = i & (TT - 1);
  out[OFF_MASK + i] = (t < xlen[b]) ? 1.0f : 0.0f;
}

extern "C" void kernel_launch(void* const* d_in, const int* in_sizes, int n_in,
                              void* d_out, int out_size, void* d_ws, size_t ws_size,
                              hipStream_t stream)
{
  (void)in_sizes; (void)n_in; (void)out_size; (void)ws_size;
  const float* emb   = (const float*)d_in[0];
  const float* Wq    = (const float*)d_in[1];
  const float* Wk    = (const float*)d_in[2];
  const float* Wv    = (const float*)d_in[3];
  const float* Wo    = (const float*)d_in[4];
  const float* bq    = (const float*)d_in[5];
  const float* bk    = (const float*)d_in[6];
  const float* bv    = (const float*)d_in[7];
  const float* bo    = (const float*)d_in[8];
  const float* relk  = (const float*)d_in[9];
  const float* relv  = (const float*)d_in[10];
  const float* ln1g  = (const float*)d_in[11];
  const float* ln1b  = (const float*)d_in[12];
  const float* ln2g  = (const float*)d_in[13];
  const float* ln2b  = (const float*)d_in[14];
  const float* W1    = (const float*)d_in[15];
  const float* b1    = (const float*)d_in[16];
  const float* W2    = (const float*)d_in[17];
  const float* b2    = (const float*)d_in[18];
  const float* projw = (const float*)d_in[19];
  const float* projb = (const float*)d_in[20];
  const int*   tokens = (const int*)d_in[21];
  const int*   xlen   = (const int*)d_in[22];
  float* out = (float*)d_out;

  // ws (12 MB): X fp32 (8MB) | pool 4MB (Qb bf16 / FFN hidden chunk)
  float* X  = (float*)d_ws;
  u16* pool = (u16*)(X + (size_t)BT * CC);
  u16* Qb = pool;
  u16* Hc = pool;
  // d_out scratch (dead before final writes):
  float* Ob = out + OFF_XBCT;
  u16*   Kb = (u16*)(out + OFF_M);
  u16*   Vb = (u16*)(out + OFF_LOGS);
  float* T5 = out + OFF_M;

  embed_k<<<(BT * CC) / 256, 256, 0, stream>>>(emb, tokens, X);

  const dim3 gC(CC / 64, BT / 64);           // (4,128)
  const dim3 gA(16, BB * HH);
  const dim3 gP((2 * OUTD) / BN, BT / BM);

  for (int l = 0; l < LL; ++l) {
    const float* Wq_l = Wq + (size_t)l * CC * CC;
    const float* Wk_l = Wk + (size_t)l * CC * CC;
    const float* Wv_l = Wv + (size_t)l * CC * CC;
    const float* Wo_l = Wo + (size_t)l * CC * CC;
    const float* rk_l = relk + (size_t)l * (2 * WSZ + 1) * HD;
    const float* rv_l = relv + (size_t)l * (2 * WSZ + 1) * HD;

    gemm_m_k<float, u16><<<gC, 256, 0, stream>>>(X, Wq_l, CC, bq + (size_t)l * CC,
                                                 Qb, CC, CC, 0.125f, 0, 0);
    gemm_m_k<float, u16><<<gC, 256, 0, stream>>>(X, Wk_l, CC, bk + (size_t)l * CC,
                                                 Kb, CC, CC, 1.0f, 0, 0);
    gemm_m_k<float, u16><<<gC, 256, 0, stream>>>(X, Wv_l, CC, bv + (size_t)l * CC,
                                                 Vb, CC, CC, 1.0f, 0, 0);
    fattn_k<<<gA, 256, 0, stream>>>(Qb, Kb, Vb, rk_l, rv_l, xlen, Ob);
    gemm_m_k<float, float><<<gC, 256, 0, stream>>>(Ob, Wo_l, CC, bo + (size_t)l * CC,
                                                   T5, CC, CC, 1.0f, 0, 0);
    addln_k<<<BT, 256, 0, stream>>>(X, T5, ln1g + (size_t)l * CC,
                                    ln1b + (size_t)l * CC, xlen, 0);
    for (int c = 0; c < 4; ++c) {
      gemm_m_k<float, u16><<<gC, 256, 0, stream>>>(X, W1 + (size_t)l * CC * FCD + c * 256,
                                                   FCD, b1 + (size_t)l * FCD + c * 256,
                                                   Hc, 256, CC, 1.0f, 1, 0);
      gemm_m_k<u16, float><<<gC, 256, 0, stream>>>(Hc,
                                                   W2 + (size_t)l * FCD * CC + (size_t)c * 256 * CC,
                                                   CC, (c == 0) ? (b2 + (size_t)l * CC) : nullptr,
                                                   T5, CC, 256, 1.0f, 0, (c > 0));
    }
    addln_k<<<BT, 256, 0, stream>>>(X, T5, ln2g + (size_t)l * CC,
                                    ln2b + (size_t)l * CC, xlen, 1);
  }

  proj_k<<<gP, 256, 0, stream>>>(X, projw, projb, xlen, out);
  pack_xbct_k<<<(BB * CC * TT) / 256, 256, 0, stream>>>(X, out);
  pack_mask_k<<<(BB * TT) / 256, 256, 0, stream>>>(xlen, out);
}

// Round 13
// 3635.662 us; speedup vs baseline: 2.8183x; 1.0653x over previous
//
#include <hip/hip_runtime.h>

typedef unsigned short u16;
typedef __attribute__((ext_vector_type(8))) short bf16x8;
typedef __attribute__((ext_vector_type(4))) float f32x4;

// Problem constants
#define CC   256
#define HH   4
#define HD   64
#define LL   6
#define FCD  1024
#define OUTD 192
#define WSZ  4
#define BB   8
#define TT   1024
#define BT   8192   // B*T

// Output flat offsets (fp32 elements)
#define OFF_XBCT 0
#define OFF_M    2097152
#define OFF_LOGS 3670016
#define OFF_MASK 5242880

__device__ __forceinline__ float bf2f(u16 u) {
  union { unsigned int i; float f; } v; v.i = ((unsigned int)u) << 16; return v.f;
}
__device__ __forceinline__ u16 f2bf(float f) {
  union { float f; unsigned int i; } v; v.f = f;
  unsigned int x = v.i;
  return (u16)((x + 0x7fffu + ((x >> 16) & 1u)) >> 16);
}
__device__ __forceinline__ void ldv4(const float* p, float* o) {
  float4 v = *reinterpret_cast<const float4*>(p);
  o[0] = v.x; o[1] = v.y; o[2] = v.z; o[3] = v.w;
}
__device__ __forceinline__ float ld_e(const float* p) { return *p; }
__device__ __forceinline__ float ld_e(const u16* p)   { return bf2f(*p); }
__device__ __forceinline__ void st_e(float* p, float v) { *p = v; }
__device__ __forceinline__ void st_e(u16* p, float v)   { *p = f2bf(v); }

// stage 8 contiguous elems of A as bf16 into d[0..7]
__device__ __forceinline__ void stage8(const float* p, u16* d) {
  float4 a = *reinterpret_cast<const float4*>(p);
  float4 b = *reinterpret_cast<const float4*>(p + 4);
  d[0] = f2bf(a.x); d[1] = f2bf(a.y); d[2] = f2bf(a.z); d[3] = f2bf(a.w);
  d[4] = f2bf(b.x); d[5] = f2bf(b.y); d[6] = f2bf(b.z); d[7] = f2bf(b.w);
}
__device__ __forceinline__ void stage8(const u16* p, u16* d) {
  ushort4 a = *reinterpret_cast<const ushort4*>(p);
  ushort4 b = *reinterpret_cast<const ushort4*>(p + 4);
  d[0] = a.x; d[1] = a.y; d[2] = a.z; d[3] = a.w;
  d[4] = b.x; d[5] = b.y; d[6] = b.z; d[7] = b.w;
}

// ---------------- Embedding ----------------
__global__ __launch_bounds__(256) void embed_k(
    const float* __restrict__ emb, const int* __restrict__ tokens,
    float* __restrict__ X)
{
  const int i = blockIdx.x * 256 + threadIdx.x;   // BT*CC
  const int bt = i >> 8;
  const int c  = i & (CC - 1);
  X[i] = emb[(size_t)tokens[bt] * CC + c] * 16.0f;
}

// ---------------- MFMA GEMM (verified round-12 core) ----------------
template <typename AT, typename CT>
__global__ __launch_bounds__(256) void gemm_m_k(
    const AT* __restrict__ A, const float* __restrict__ W, int ldb,
    const float* __restrict__ bias, CT* __restrict__ C, int ldc,
    int K, float ps, int relu, int accum)
{
  __shared__ u16 As[64][40];
  __shared__ u16 Bs[64][40];
  const int tid  = threadIdx.x;
  const int lane = tid & 63;
  const int wv   = tid >> 6;
  const int bm = blockIdx.y * 64;
  const int bn = blockIdx.x * 64;
  const int l15 = lane & 15;
  const int lq  = lane >> 4;
  const int ar = tid >> 2;
  const int ak = (tid & 3) << 3;
  const int kr = tid & 31;
  const int nb = (tid >> 5) << 3;

  f32x4 acc[4];
#pragma unroll
  for (int nt = 0; nt < 4; ++nt) acc[nt] = (f32x4){0.0f, 0.0f, 0.0f, 0.0f};

  for (int k0 = 0; k0 < K; k0 += 32) {
    u16 t8[8];
    stage8(A + (size_t)(bm + ar) * K + (k0 + ak), t8);
    *reinterpret_cast<ushort4*>(&As[ar][ak]) =
        make_ushort4(t8[0], t8[1], t8[2], t8[3]);
    *reinterpret_cast<ushort4*>(&As[ar][ak + 4]) =
        make_ushort4(t8[4], t8[5], t8[6], t8[7]);
    float w8[8];
    ldv4(W + (size_t)(k0 + kr) * ldb + (bn + nb), w8);
    ldv4(W + (size_t)(k0 + kr) * ldb + (bn + nb + 4), w8 + 4);
#pragma unroll
    for (int j = 0; j < 8; ++j) Bs[nb + j][kr] = f2bf(w8[j]);
    __syncthreads();

    const bf16x8 af = *reinterpret_cast<const bf16x8*>(&As[(wv << 4) + l15][lq << 3]);
#pragma unroll
    for (int nt = 0; nt < 4; ++nt) {
      const bf16x8 bf = *reinterpret_cast<const bf16x8*>(&Bs[(nt << 4) + l15][lq << 3]);
      acc[nt] = __builtin_amdgcn_mfma_f32_16x16x32_bf16(af, bf, acc[nt], 0, 0, 0);
    }
    __syncthreads();
  }

#pragma unroll
  for (int nt = 0; nt < 4; ++nt) {
#pragma unroll
    for (int r = 0; r < 4; ++r) {
      const int row = bm + (wv << 4) + (lq << 2) + r;
      const int col = bn + (nt << 4) + l15;
      float vv = acc[nt][r];
      if (bias) vv += bias[col];
      vv *= ps;
      if (relu) vv = fmaxf(vv, 0.0f);
      const size_t ci = (size_t)row * ldc + col;
      if (accum) vv += ld_e(C + ci);
      st_e(C + ci, vv);
    }
  }
}

// ---------------- Flash attention: block = (qtile 64, b, h) ----------------
// Kl stride 70 (140B rows): lane step 140 dwords ≡ 12 mod 32 -> 8 banks, 2-way (free).
__global__ __launch_bounds__(256) void fattn_k(
    const u16* __restrict__ Qb, const u16* __restrict__ Kb,
    const u16* __restrict__ Vb, const float* __restrict__ rk,
    const float* __restrict__ rv, const int* __restrict__ xlen,
    float* __restrict__ Ob)
{
  __shared__ u16  Ql[64][72];
  __shared__ u16  Kl[64][70];
  __shared__ u16  Vl[64][72];
  __shared__ float Sb[64][68];
  __shared__ float rkl[9][64];
  __shared__ float rvl[9][68];
  __shared__ float qrel[64][9];
  __shared__ float mrow[64], lrow[64], arow[64];
  __shared__ float pmax[64][4], psum[64][4];

  const int qt = blockIdx.x;
  const int bh = blockIdx.y;
  const int b  = bh >> 2;
  const int h  = bh & 3;
  const int tid = threadIdx.x;
  const int len = xlen[b];
  const int q0  = qt << 6;

  for (int i = tid; i < 9 * 64; i += 256) {
    rkl[i >> 6][i & 63] = rk[i];
    rvl[i >> 6][i & 63] = rv[i];
  }
  for (int i = tid; i < 64 * 16; i += 256) {
    const int r = i >> 4, c4 = (i & 15) << 2;
    ushort4 v = *reinterpret_cast<const ushort4*>(
        Qb + (size_t)((b << 10) + q0 + r) * CC + (h << 6) + c4);
    Ql[r][c4] = v.x; Ql[r][c4 + 1] = v.y; Ql[r][c4 + 2] = v.z; Ql[r][c4 + 3] = v.w;
  }
  if (tid < 64) { mrow[tid] = -3.0e38f; lrow[tid] = 0.0f; }
  __syncthreads();
  for (int i = tid; i < 64 * 9; i += 256) {
    const int r = i / 9, j = i - r * 9;
    float s = 0.0f;
#pragma unroll 16
    for (int d = 0; d < 64; ++d) s += bf2f(Ql[r][d]) * rkl[j][d];
    qrel[r][j] = s;
  }
  __syncthreads();

  const int tq = (tid >> 4) << 2;
  const int tk = (tid & 15) << 2;
  float O[4][4] = {{0.0f}};

  for (int kt = 0; kt < 16; ++kt) {
    const int k0 = kt << 6;
    for (int i = tid; i < 64 * 16; i += 256) {
      const int r = i >> 4, c4 = (i & 15) << 2;
      const size_t g = (size_t)((b << 10) + k0 + r) * CC + (h << 6) + c4;
      ushort4 kv = *reinterpret_cast<const ushort4*>(Kb + g);
      *reinterpret_cast<ushort2*>(&Kl[r][c4])     = make_ushort2(kv.x, kv.y);
      *reinterpret_cast<ushort2*>(&Kl[r][c4 + 2]) = make_ushort2(kv.z, kv.w);
      ushort4 vv = *reinterpret_cast<const ushort4*>(Vb + g);
      Vl[r][c4] = vv.x; Vl[r][c4 + 1] = vv.y; Vl[r][c4 + 2] = vv.z; Vl[r][c4 + 3] = vv.w;
    }
    __syncthreads();

    float S[4][4] = {{0.0f}};
    for (int d = 0; d < 64; d += 4) {
      float qv[4][4], kv[4][4];
#pragma unroll
      for (int i = 0; i < 4; ++i) {
        ushort4 t = *reinterpret_cast<const ushort4*>(&Ql[tq + i][d]);
        qv[i][0] = bf2f(t.x); qv[i][1] = bf2f(t.y);
        qv[i][2] = bf2f(t.z); qv[i][3] = bf2f(t.w);
        ushort2 u0 = *reinterpret_cast<const ushort2*>(&Kl[tk + i][d]);
        ushort2 u1 = *reinterpret_cast<const ushort2*>(&Kl[tk + i][d + 2]);
        kv[i][0] = bf2f(u0.x); kv[i][1] = bf2f(u0.y);
        kv[i][2] = bf2f(u1.x); kv[i][3] = bf2f(u1.y);
      }
#pragma unroll
      for (int i = 0; i < 4; ++i)
#pragma unroll
        for (int j = 0; j < 4; ++j)
          S[i][j] += qv[i][0] * kv[j][0] + qv[i][1] * kv[j][1]
                   + qv[i][2] * kv[j][2] + qv[i][3] * kv[j][3];
    }
#pragma unroll
    for (int i = 0; i < 4; ++i) {
      const int q = q0 + tq + i;
#pragma unroll
      for (int j = 0; j < 4; ++j) {
        const int k = k0 + tk + j;
        float s = S[i][j];
        const int r = k - q;
        if (r >= -WSZ && r <= WSZ) s += qrel[tq + i][r + WSZ];
        if (q >= len || k >= len) s = -10000.0f;
        Sb[tq + i][tk + j] = s;
      }
    }
    __syncthreads();
    {
      const int row = tid >> 2, seg = tid & 3;
      float m = -3.0e38f;
      for (int c = seg * 16; c < seg * 16 + 16; ++c) m = fmaxf(m, Sb[row][c]);
      pmax[row][seg] = m;
    }
    __syncthreads();
    if (tid < 64) {
      const float mo = mrow[tid];
      float mn = fmaxf(fmaxf(pmax[tid][0], pmax[tid][1]),
                       fmaxf(pmax[tid][2], pmax[tid][3]));
      mn = fmaxf(mo, mn);
      const float a = __expf(mo - mn);
      mrow[tid] = mn; arow[tid] = a;
      lrow[tid] *= a;
    }
    __syncthreads();
    {
      const int row = tid >> 2, seg = tid & 3;
      const float mn = mrow[row];
      float s = 0.0f;
      for (int c = seg * 16; c < seg * 16 + 16; ++c) {
        const float p = __expf(Sb[row][c] - mn);
        Sb[row][c] = p; s += p;
      }
      psum[row][seg] = s;
    }
    __syncthreads();
    if (tid < 64)
      lrow[tid] += psum[tid][0] + psum[tid][1] + psum[tid][2] + psum[tid][3];

#pragma unroll
    for (int i = 0; i < 4; ++i) {
      const float a = arow[tq + i];
      O[i][0] *= a; O[i][1] *= a; O[i][2] *= a; O[i][3] *= a;
    }
    for (int kk = 0; kk < 64; kk += 4) {
      float pv[4][4], vv[4][4];
#pragma unroll
      for (int i = 0; i < 4; ++i) {
        float4 t = *reinterpret_cast<const float4*>(&Sb[tq + i][kk]);
        pv[i][0] = t.x; pv[i][1] = t.y; pv[i][2] = t.z; pv[i][3] = t.w;
        ushort4 u = *reinterpret_cast<const ushort4*>(&Vl[kk + i][tk]);
        vv[i][0] = bf2f(u.x); vv[i][1] = bf2f(u.y);
        vv[i][2] = bf2f(u.z); vv[i][3] = bf2f(u.w);
      }
#pragma unroll
      for (int i = 0; i < 4; ++i)
#pragma unroll
        for (int j = 0; j < 4; ++j)
          O[i][j] += pv[i][0] * vv[0][j] + pv[i][1] * vv[1][j]
                   + pv[i][2] * vv[2][j] + pv[i][3] * vv[3][j];
    }
#pragma unroll
    for (int i = 0; i < 4; ++i) {
      const int q = q0 + tq + i;
#pragma unroll
      for (int r = -WSZ; r <= WSZ; ++r) {
        const int k = q + r;
        if (k >= k0 && k < k0 + 64) {
          const float p = Sb[tq + i][k - k0];
          O[i][0] += p * rvl[r + WSZ][tk + 0];
          O[i][1] += p * rvl[r + WSZ][tk + 1];
          O[i][2] += p * rvl[r + WSZ][tk + 2];
          O[i][3] += p * rvl[r + WSZ][tk + 3];
        }
      }
    }
    __syncthreads();
  }

#pragma unroll
  for (int i = 0; i < 4; ++i) {
    const float inv = 1.0f / lrow[tq + i];
    float4 o;
    o.x = O[i][0] * inv; o.y = O[i][1] * inv;
    o.z = O[i][2] * inv; o.w = O[i][3] * inv;
    *reinterpret_cast<float4*>(
        Ob + (size_t)((b << 10) + q0 + tq + i) * CC + (h << 6) + tk) = o;
  }
}

// ---------------- Residual add + LayerNorm ----------------
__global__ __launch_bounds__(256) void addln_k(
    float* __restrict__ X, const float* __restrict__ R,
    const float* __restrict__ g, const float* __restrict__ be,
    const int* __restrict__ xlen, int am)
{
  __shared__ float red[256];
  const int row = blockIdx.x;
  const int tid = threadIdx.x;
  const int b = row >> 10;
  const int t = row & (TT - 1);
  const size_t base = (size_t)row * CC;
  const float v = X[base + tid] + R[base + tid];
  red[tid] = v; __syncthreads();
  for (int s2 = 128; s2 > 0; s2 >>= 1) {
    if (tid < s2) red[tid] += red[tid + s2];
    __syncthreads();
  }
  const float mean = red[0] * (1.0f / CC);
  __syncthreads();
  const float dv = v - mean;
  red[tid] = dv * dv; __syncthreads();
  for (int s2 = 128; s2 > 0; s2 >>= 1) {
    if (tid < s2) red[tid] += red[tid + s2];
    __syncthreads();
  }
  const float var = red[0] * (1.0f / CC);
  float y = dv * rsqrtf(var + 1e-5f) * g[tid] + be[tid];
  if (am && t >= xlen[b]) y = 0.0f;
  X[base + tid] = y;
}

// ---------------- Final projection -> fp32 m/logs, masked ----------------
#define BM 64
#define BN 64
#define BK 16
__global__ __launch_bounds__(256) void proj_k(
    const float* __restrict__ A, const float* __restrict__ W,
    const float* __restrict__ bias, const int* __restrict__ xlen,
    float* __restrict__ out)
{
  __shared__ float As[BK][BM + 1];
  __shared__ float Bs[BK][BN + 1];
  const int tid = threadIdx.x;
  const int bm = blockIdx.y * BM;
  const int bn = blockIdx.x * BN;
  const int tr = (tid >> 4) << 2;
  const int tc = (tid & 15) << 2;
  const int ar = tid >> 2;
  const int ac = (tid & 3) << 2;
  float acc[4][4] = {{0.0f}};
  float tmp[4];
  for (int k0 = 0; k0 < CC; k0 += BK) {
    ldv4(A + (size_t)(bm + ar) * CC + (k0 + ac), tmp);
    As[ac + 0][ar] = tmp[0]; As[ac + 1][ar] = tmp[1];
    As[ac + 2][ar] = tmp[2]; As[ac + 3][ar] = tmp[3];
    const int nn = tid >> 2;
    const int kx = (tid & 3) << 2;
    ldv4(W + (size_t)(bn + nn) * CC + (k0 + kx), tmp);
    Bs[kx + 0][nn] = tmp[0]; Bs[kx + 1][nn] = tmp[1];
    Bs[kx + 2][nn] = tmp[2]; Bs[kx + 3][nn] = tmp[3];
    __syncthreads();
#pragma unroll
    for (int kk = 0; kk < BK; ++kk) {
      const float a0 = As[kk][tr + 0], a1 = As[kk][tr + 1];
      const float a2 = As[kk][tr + 2], a3 = As[kk][tr + 3];
      const float b0 = Bs[kk][tc + 0], b1 = Bs[kk][tc + 1];
      const float b2 = Bs[kk][tc + 2], b3 = Bs[kk][tc + 3];
      acc[0][0] += a0 * b0; acc[0][1] += a0 * b1; acc[0][2] += a0 * b2; acc[0][3] += a0 * b3;
      acc[1][0] += a1 * b0; acc[1][1] += a1 * b1; acc[1][2] += a1 * b2; acc[1][3] += a1 * b3;
      acc[2][0] += a2 * b0; acc[2][1] += a2 * b1; acc[2][2] += a2 * b2; acc[2][3] += a2 * b3;
      acc[3][0] += a3 * b0; acc[3][1] += a3 * b1; acc[3][2] += a3 * b2; acc[3][3] += a3 * b3;
    }
    __syncthreads();
  }
#pragma unroll
  for (int i = 0; i < 4; ++i) {
    const int row = bm + tr + i;
    const int b = row >> 10;
    const int t = row & (TT - 1);
    const int len = xlen[b];
#pragma unroll
    for (int j = 0; j < 4; ++j) {
      const int o = bn + tc + j;
      float vv = acc[i][j] + bias[o];
      if (t >= len) vv = 0.0f;
      const size_t dst = (o < OUTD)
          ? (size_t)OFF_M    + ((size_t)b * OUTD + o) * TT + t
          : (size_t)OFF_LOGS + ((size_t)b * OUTD + (o - OUTD)) * TT + t;
      out[dst] = vv;
    }
  }
}

// ---------------- Output packing ----------------
__global__ __launch_bounds__(256) void pack_xbct_k(
    const float* __restrict__ X, float* __restrict__ out)
{
  const int i = blockIdx.x * 256 + threadIdx.x;
  const int b = i >> 18;
  const int c = (i >> 10) & (CC - 1);
  const int t = i & (TT - 1);
  out[OFF_XBCT + i] = X[((size_t)b << 18) + ((size_t)t << 8) + c];
}

__global__ __launch_bounds__(256) void pack_mask_k(
    const int* __restrict__ xlen, float* __restrict__ out)
{
  const int i = blockIdx.x * 256 + threadIdx.x;
  const int b = i >> 10;
  const int t = i & (TT - 1);
  out[OFF_MASK + i] = (t < xlen[b]) ? 1.0f : 0.0f;
}

extern "C" void kernel_launch(void* const* d_in, const int* in_sizes, int n_in,
                              void* d_out, int out_size, void* d_ws, size_t ws_size,
                              hipStream_t stream)
{
  (void)in_sizes; (void)n_in; (void)out_size; (void)ws_size;
  const float* emb   = (const float*)d_in[0];
  const float* Wq    = (const float*)d_in[1];
  const float* Wk    = (const float*)d_in[2];
  const float* Wv    = (const float*)d_in[3];
  const float* Wo    = (const float*)d_in[4];
  const float* bq    = (const float*)d_in[5];
  const float* bk    = (const float*)d_in[6];
  const float* bv    = (const float*)d_in[7];
  const float* bo    = (const float*)d_in[8];
  const float* relk  = (const float*)d_in[9];
  const float* relv  = (const float*)d_in[10];
  const float* ln1g  = (const float*)d_in[11];
  const float* ln1b  = (const float*)d_in[12];
  const float* ln2g  = (const float*)d_in[13];
  const float* ln2b  = (const float*)d_in[14];
  const float* W1    = (const float*)d_in[15];
  const float* b1    = (const float*)d_in[16];
  const float* W2    = (const float*)d_in[17];
  const float* b2    = (const float*)d_in[18];
  const float* projw = (const float*)d_in[19];
  const float* projb = (const float*)d_in[20];
  const int*   tokens = (const int*)d_in[21];
  const int*   xlen   = (const int*)d_in[22];
  float* out = (float*)d_out;

  float* X  = (float*)d_ws;
  u16* pool = (u16*)(X + (size_t)BT * CC);
  u16* Qb = pool;
  u16* Hc = pool;
  float* Ob = out + OFF_XBCT;
  u16*   Kb = (u16*)(out + OFF_M);
  u16*   Vb = (u16*)(out + OFF_LOGS);
  float* T5 = out + OFF_M;

  embed_k<<<(BT * CC) / 256, 256, 0, stream>>>(emb, tokens, X);

  const dim3 gC(CC / 64, BT / 64);
  const dim3 gA(16, BB * HH);
  const dim3 gP((2 * OUTD) / BN, BT / BM);

  for (int l = 0; l < LL; ++l) {
    const float* Wq_l = Wq + (size_t)l * CC * CC;
    const float* Wk_l = Wk + (size_t)l * CC * CC;
    const float* Wv_l = Wv + (size_t)l * CC * CC;
    const float* Wo_l = Wo + (size_t)l * CC * CC;
    const float* rk_l = relk + (size_t)l * (2 * WSZ + 1) * HD;
    const float* rv_l = relv + (size_t)l * (2 * WSZ + 1) * HD;

    gemm_m_k<float, u16><<<gC, 256, 0, stream>>>(X, Wq_l, CC, bq + (size_t)l * CC,
                                                 Qb, CC, CC, 0.125f, 0, 0);
    gemm_m_k<float, u16><<<gC, 256, 0, stream>>>(X, Wk_l, CC, bk + (size_t)l * CC,
                                                 Kb, CC, CC, 1.0f, 0, 0);
    gemm_m_k<float, u16><<<gC, 256, 0, stream>>>(X, Wv_l, CC, bv + (size_t)l * CC,
                                                 Vb, CC, CC, 1.0f, 0, 0);
    fattn_k<<<gA, 256, 0, stream>>>(Qb, Kb, Vb, rk_l, rv_l, xlen, Ob);
    gemm_m_k<float, float><<<gC, 256, 0, stream>>>(Ob, Wo_l, CC, bo + (size_t)l * CC,
                                                   T5, CC, CC, 1.0f, 0, 0);
    addln_k<<<BT, 256, 0, stream>>>(X, T5, ln1g + (size_t)l * CC,
                                    ln1b + (size_t)l * CC, xlen, 0);
    for (int c = 0; c < 4; ++c) {
      gemm_m_k<float, u16><<<gC, 256, 0, stream>>>(X, W1 + (size_t)l * CC * FCD + c * 256,
                                                   FCD, b1 + (size_t)l * FCD + c * 256,
                                                   Hc, 256, CC, 1.0f, 1, 0);
      gemm_m_k<u16, float><<<gC, 256, 0, stream>>>(Hc,
                                                   W2 + (size_t)l * FCD * CC + (size_t)c * 256 * CC,
                                                   CC, (c == 0) ? (b2 + (size_t)l * CC) : nullptr,
                                                   T5, CC, 256, 1.0f, 0, (c > 0));
    }
    addln_k<<<BT, 256, 0, stream>>>(X, T5, ln2g + (size_t)l * CC,
                                    ln2b + (size_t)l * CC, xlen, 1);
  }

  proj_k<<<gP, 256, 0, stream>>>(X, projw, projb, xlen, out);
  pack_xbct_k<<<(BB * CC * TT) / 256, 256, 0, stream>>>(X, out);
  pack_mask_k<<<(BB * TT) / 256, 256, 0, stream>>>(xlen, out);
}

// Round 14
// 1743.608 us; speedup vs baseline: 5.8765x; 2.0851x over previous
//
#include <hip/hip_runtime.h>

typedef unsigned short u16;
typedef __attribute__((ext_vector_type(8))) short bf16x8;
typedef __attribute__((ext_vector_type(4))) float f32x4;

// Problem constants
#define CC   256
#define HH   4
#define HD   64
#define LL   6
#define FCD  1024
#define OUTD 192
#define WSZ  4
#define BB   8
#define TT   1024
#define BT   8192   // B*T

// Output flat offsets (fp32 elements)
#define OFF_XBCT 0
#define OFF_M    2097152
#define OFF_LOGS 3670016
#define OFF_MASK 5242880

__device__ __forceinline__ float bf2f(u16 u) {
  union { unsigned int i; float f; } v; v.i = ((unsigned int)u) << 16; return v.f;
}
__device__ __forceinline__ u16 f2bf(float f) {
  union { float f; unsigned int i; } v; v.f = f;
  unsigned int x = v.i;
  return (u16)((x + 0x7fffu + ((x >> 16) & 1u)) >> 16);
}
__device__ __forceinline__ void ldv4(const float* p, float* o) {
  float4 v = *reinterpret_cast<const float4*>(p);
  o[0] = v.x; o[1] = v.y; o[2] = v.z; o[3] = v.w;
}
__device__ __forceinline__ float ld_e(const float* p) { return *p; }
__device__ __forceinline__ float ld_e(const u16* p)   { return bf2f(*p); }
__device__ __forceinline__ void st_e(float* p, float v) { *p = v; }
__device__ __forceinline__ void st_e(u16* p, float v)   { *p = f2bf(v); }

// stage 8 contiguous elems of A as bf16 into d[0..7]
__device__ __forceinline__ void stage8(const float* p, u16* d) {
  float4 a = *reinterpret_cast<const float4*>(p);
  float4 b = *reinterpret_cast<const float4*>(p + 4);
  d[0] = f2bf(a.x); d[1] = f2bf(a.y); d[2] = f2bf(a.z); d[3] = f2bf(a.w);
  d[4] = f2bf(b.x); d[5] = f2bf(b.y); d[6] = f2bf(b.z); d[7] = f2bf(b.w);
}
__device__ __forceinline__ void stage8(const u16* p, u16* d) {
  ushort4 a = *reinterpret_cast<const ushort4*>(p);
  ushort4 b = *reinterpret_cast<const ushort4*>(p + 4);
  d[0] = a.x; d[1] = a.y; d[2] = a.z; d[3] = a.w;
  d[4] = b.x; d[5] = b.y; d[6] = b.z; d[7] = b.w;
}

// ---------------- Embedding ----------------
__global__ __launch_bounds__(256) void embed_k(
    const float* __restrict__ emb, const int* __restrict__ tokens,
    float* __restrict__ X)
{
  const int i = blockIdx.x * 256 + threadIdx.x;   // BT*CC
  const int bt = i >> 8;
  const int c  = i & (CC - 1);
  X[i] = emb[(size_t)tokens[bt] * CC + c] * 16.0f;
}

// ---------------- MFMA GEMM (verified round-12 core) ----------------
template <typename AT, typename CT>
__global__ __launch_bounds__(256) void gemm_m_k(
    const AT* __restrict__ A, const float* __restrict__ W, int ldb,
    const float* __restrict__ bias, CT* __restrict__ C, int ldc,
    int K, float ps, int relu, int accum)
{
  __shared__ u16 As[64][40];
  __shared__ u16 Bs[64][40];
  const int tid  = threadIdx.x;
  const int lane = tid & 63;
  const int wv   = tid >> 6;
  const int bm = blockIdx.y * 64;
  const int bn = blockIdx.x * 64;
  const int l15 = lane & 15;
  const int lq  = lane >> 4;
  const int ar = tid >> 2;
  const int ak = (tid & 3) << 3;
  const int kr = tid & 31;
  const int nb = (tid >> 5) << 3;

  f32x4 acc[4];
#pragma unroll
  for (int nt = 0; nt < 4; ++nt) acc[nt] = (f32x4){0.0f, 0.0f, 0.0f, 0.0f};

  for (int k0 = 0; k0 < K; k0 += 32) {
    u16 t8[8];
    stage8(A + (size_t)(bm + ar) * K + (k0 + ak), t8);
    *reinterpret_cast<ushort4*>(&As[ar][ak]) =
        make_ushort4(t8[0], t8[1], t8[2], t8[3]);
    *reinterpret_cast<ushort4*>(&As[ar][ak + 4]) =
        make_ushort4(t8[4], t8[5], t8[6], t8[7]);
    float w8[8];
    ldv4(W + (size_t)(k0 + kr) * ldb + (bn + nb), w8);
    ldv4(W + (size_t)(k0 + kr) * ldb + (bn + nb + 4), w8 + 4);
#pragma unroll
    for (int j = 0; j < 8; ++j) Bs[nb + j][kr] = f2bf(w8[j]);
    __syncthreads();

    const bf16x8 af = *reinterpret_cast<const bf16x8*>(&As[(wv << 4) + l15][lq << 3]);
#pragma unroll
    for (int nt = 0; nt < 4; ++nt) {
      const bf16x8 bf = *reinterpret_cast<const bf16x8*>(&Bs[(nt << 4) + l15][lq << 3]);
      acc[nt] = __builtin_amdgcn_mfma_f32_16x16x32_bf16(af, bf, acc[nt], 0, 0, 0);
    }
    __syncthreads();
  }

#pragma unroll
  for (int nt = 0; nt < 4; ++nt) {
#pragma unroll
    for (int r = 0; r < 4; ++r) {
      const int row = bm + (wv << 4) + (lq << 2) + r;
      const int col = bn + (nt << 4) + l15;
      float vv = acc[nt][r];
      if (bias) vv += bias[col];
      vv *= ps;
      if (relu) vv = fmaxf(vv, 0.0f);
      const size_t ci = (size_t)row * ldc + col;
      if (accum) vv += ld_e(C + ci);
      st_e(C + ci, vv);
    }
  }
}

// ---------------- Flash attention (MFMA QK^T + PV): block = (qtile 64, b, h) ----------------
// D[m][n] = sum_k Afrag[m][k]*Bfrag[n][k] (both row-major-by-k; verified via gemm_m_k).
// QK^T: A=Ql[q][d], B=Kl[kpos][d].  PV: A=Pl[q][kpos] (bf16 probs), B=Vt[d][kpos].
__global__ __launch_bounds__(256) void fattn_k(
    const u16* __restrict__ Qb, const u16* __restrict__ Kb,
    const u16* __restrict__ Vb, const float* __restrict__ rk,
    const float* __restrict__ rv, const int* __restrict__ xlen,
    float* __restrict__ Ob)
{
  __shared__ u16  Ql[64][72];
  __shared__ u16  Kl[64][72];
  __shared__ u16  Vt[64][72];   // Vt[d][kpos] = V[kpos][d]
  __shared__ u16  Pl[64][72];   // probs bf16, A-frag source for PV
  __shared__ float Sb[64][68];
  __shared__ float rkl[9][64];
  __shared__ float rvl[9][68];
  __shared__ float qrel[64][12];  // q·rel_k band; reused as pband at the end
  __shared__ float bs[64][12];    // saved band scores
  __shared__ float mrow[64], lrow[64], arow[64];
  __shared__ float pmax[64][4], psum[64][4];

  const int qt = blockIdx.x;
  const int bh = blockIdx.y;
  const int b  = bh >> 2;
  const int h  = bh & 3;
  const int tid  = threadIdx.x;
  const int lane = tid & 63;
  const int wv   = tid >> 6;
  const int l15  = lane & 15;
  const int lq   = lane >> 4;
  const int len = xlen[b];
  const int q0  = qt << 6;
  const int m0  = wv << 4;

  for (int i = tid; i < 9 * 64; i += 256) {
    rkl[i >> 6][i & 63] = rk[i];
    rvl[i >> 6][i & 63] = rv[i];
  }
  for (int i = tid; i < 64 * 16; i += 256) {
    const int r = i >> 4, c4 = (i & 15) << 2;
    *reinterpret_cast<ushort4*>(&Ql[r][c4]) = *reinterpret_cast<const ushort4*>(
        Qb + (size_t)((b << 10) + q0 + r) * CC + (h << 6) + c4);
  }
  if (tid < 64) { mrow[tid] = -3.0e38f; lrow[tid] = 0.0f; }
  for (int i = tid; i < 64 * 12; i += 256) (&bs[0][0])[i] = -3.0e38f;
  __syncthreads();
  for (int i = tid; i < 64 * 9; i += 256) {
    const int r = i / 9, j = i - r * 9;
    float s = 0.0f;
#pragma unroll 16
    for (int d = 0; d < 64; ++d) s += bf2f(Ql[r][d]) * rkl[j][d];
    qrel[r][j] = s;
  }
  __syncthreads();

  f32x4 oacc[4];
#pragma unroll
  for (int nt = 0; nt < 4; ++nt) oacc[nt] = (f32x4){0.0f, 0.0f, 0.0f, 0.0f};

  for (int kt = 0; kt < 16; ++kt) {
    const int k0 = kt << 6;
    // stage K (row-major) and V (transposed)
    for (int i = tid; i < 64 * 16; i += 256) {
      const int r = i >> 4, c4 = (i & 15) << 2;
      *reinterpret_cast<ushort4*>(&Kl[r][c4]) = *reinterpret_cast<const ushort4*>(
          Kb + (size_t)((b << 10) + k0 + r) * CC + (h << 6) + c4);
    }
    {
      const int d = lane;          // 0..63
      const int rg = wv;           // 0..3 -> kpos group of 16
      u16 v16[16];
#pragma unroll
      for (int s = 0; s < 16; ++s)
        v16[s] = Vb[(size_t)((b << 10) + k0 + rg * 16 + s) * CC + (h << 6) + d];
#pragma unroll
      for (int t = 0; t < 4; ++t)
        *reinterpret_cast<ushort4*>(&Vt[d][rg * 16 + t * 4]) =
            make_ushort4(v16[t*4], v16[t*4+1], v16[t*4+2], v16[t*4+3]);
    }
    __syncthreads();

    // S = Q @ K^T via MFMA
    f32x4 sacc[4];
#pragma unroll
    for (int nt = 0; nt < 4; ++nt) sacc[nt] = (f32x4){0.0f, 0.0f, 0.0f, 0.0f};
    {
      const bf16x8 a0 = *reinterpret_cast<const bf16x8*>(&Ql[m0 + l15][lq << 3]);
      const bf16x8 a1 = *reinterpret_cast<const bf16x8*>(&Ql[m0 + l15][32 + (lq << 3)]);
#pragma unroll
      for (int nt = 0; nt < 4; ++nt) {
        const bf16x8 b0 = *reinterpret_cast<const bf16x8*>(&Kl[(nt << 4) + l15][lq << 3]);
        const bf16x8 b1 = *reinterpret_cast<const bf16x8*>(&Kl[(nt << 4) + l15][32 + (lq << 3)]);
        sacc[nt] = __builtin_amdgcn_mfma_f32_16x16x32_bf16(a0, b0, sacc[nt], 0, 0, 0);
        sacc[nt] = __builtin_amdgcn_mfma_f32_16x16x32_bf16(a1, b1, sacc[nt], 0, 0, 0);
      }
    }
    // write S (+qrel band, mask) to Sb; save band scores
#pragma unroll
    for (int nt = 0; nt < 4; ++nt) {
#pragma unroll
      for (int reg = 0; reg < 4; ++reg) {
        const int m = m0 + (lq << 2) + reg;
        const int q = q0 + m;
        const int k = k0 + (nt << 4) + l15;
        float s = sacc[nt][reg];
        const int r = k - q;
        const bool band = (r >= -WSZ && r <= WSZ);
        if (band) s += qrel[m][r + WSZ];
        if (q >= len || k >= len) s = -10000.0f;
        Sb[m][(nt << 4) + l15] = s;
        if (band) bs[m][r + WSZ] = s;
      }
    }
    __syncthreads();
    {
      const int row = tid >> 2, seg = tid & 3;
      float mx = -3.0e38f;
      for (int c = seg * 16; c < seg * 16 + 16; ++c) mx = fmaxf(mx, Sb[row][c]);
      pmax[row][seg] = mx;
    }
    __syncthreads();
    if (tid < 64) {
      const float mo = mrow[tid];
      float mn = fmaxf(fmaxf(pmax[tid][0], pmax[tid][1]),
                       fmaxf(pmax[tid][2], pmax[tid][3]));
      mn = fmaxf(mo, mn);
      const float a = __expf(mo - mn);
      mrow[tid] = mn; arow[tid] = a;
      lrow[tid] *= a;
    }
    __syncthreads();
    {
      const int row = tid >> 2, seg = tid & 3;
      const float mn = mrow[row];
      float ssum = 0.0f;
#pragma unroll
      for (int t = 0; t < 4; ++t) {
        u16 pk[4];
#pragma unroll
        for (int j = 0; j < 4; ++j) {
          const float p = __expf(Sb[row][seg * 16 + t * 4 + j] - mn);
          ssum += p; pk[j] = f2bf(p);
        }
        *reinterpret_cast<ushort4*>(&Pl[row][seg * 16 + t * 4]) =
            make_ushort4(pk[0], pk[1], pk[2], pk[3]);
      }
      psum[row][seg] = ssum;
    }
    __syncthreads();
    if (tid < 64)
      lrow[tid] += psum[tid][0] + psum[tid][1] + psum[tid][2] + psum[tid][3];

    // O = alpha*O + P @ V via MFMA
    {
      float a_r[4];
#pragma unroll
      for (int reg = 0; reg < 4; ++reg) a_r[reg] = arow[m0 + (lq << 2) + reg];
#pragma unroll
      for (int nt = 0; nt < 4; ++nt) {
#pragma unroll
        for (int reg = 0; reg < 4; ++reg) oacc[nt][reg] *= a_r[reg];
      }
      const bf16x8 p0 = *reinterpret_cast<const bf16x8*>(&Pl[m0 + l15][lq << 3]);
      const bf16x8 p1 = *reinterpret_cast<const bf16x8*>(&Pl[m0 + l15][32 + (lq << 3)]);
#pragma unroll
      for (int nt = 0; nt < 4; ++nt) {
        const bf16x8 v0 = *reinterpret_cast<const bf16x8*>(&Vt[(nt << 4) + l15][lq << 3]);
        const bf16x8 v1 = *reinterpret_cast<const bf16x8*>(&Vt[(nt << 4) + l15][32 + (lq << 3)]);
        oacc[nt] = __builtin_amdgcn_mfma_f32_16x16x32_bf16(p0, v0, oacc[nt], 0, 0, 0);
        oacc[nt] = __builtin_amdgcn_mfma_f32_16x16x32_bf16(p1, v1, oacc[nt], 0, 0, 0);
      }
    }
    __syncthreads();
  }

  // band rel_v contribution (exact: exp(bs - m_final)) + normalize + store
  for (int i = tid; i < 64 * 9; i += 256) {
    const int r = i / 9, j = i - r * 9;
    qrel[r][j] = __expf(bs[r][j] - mrow[r]);   // reuse qrel as pband
  }
  __syncthreads();
#pragma unroll
  for (int nt = 0; nt < 4; ++nt) {
#pragma unroll
    for (int reg = 0; reg < 4; ++reg) {
      const int m = m0 + (lq << 2) + reg;
      float o = oacc[nt][reg];
#pragma unroll
      for (int j = 0; j < 9; ++j) o += qrel[m][j] * rvl[j][(nt << 4) + l15];
      o *= 1.0f / lrow[m];
      Ob[(size_t)((b << 10) + q0 + m) * CC + (h << 6) + (nt << 4) + l15] = o;
    }
  }
}

// ---------------- Residual add + LayerNorm ----------------
__global__ __launch_bounds__(256) void addln_k(
    float* __restrict__ X, const float* __restrict__ R,
    const float* __restrict__ g, const float* __restrict__ be,
    const int* __restrict__ xlen, int am)
{
  __shared__ float red[256];
  const int row = blockIdx.x;
  const int tid = threadIdx.x;
  const int b = row >> 10;
  const int t = row & (TT - 1);
  const size_t base = (size_t)row * CC;
  const float v = X[base + tid] + R[base + tid];
  red[tid] = v; __syncthreads();
  for (int s2 = 128; s2 > 0; s2 >>= 1) {
    if (tid < s2) red[tid] += red[tid + s2];
    __syncthreads();
  }
  const float mean = red[0] * (1.0f / CC);
  __syncthreads();
  const float dv = v - mean;
  red[tid] = dv * dv; __syncthreads();
  for (int s2 = 128; s2 > 0; s2 >>= 1) {
    if (tid < s2) red[tid] += red[tid + s2];
    __syncthreads();
  }
  const float var = red[0] * (1.0f / CC);
  float y = dv * rsqrtf(var + 1e-5f) * g[tid] + be[tid];
  if (am && t >= xlen[b]) y = 0.0f;
  X[base + tid] = y;
}

// ---------------- Final projection -> fp32 m/logs, masked ----------------
#define BM 64
#define BN 64
#define BK 16
__global__ __launch_bounds__(256) void proj_k(
    const float* __restrict__ A, const float* __restrict__ W,
    const float* __restrict__ bias, const int* __restrict__ xlen,
    float* __restrict__ out)
{
  __shared__ float As[BK][BM + 1];
  __shared__ float Bs[BK][BN + 1];
  const int tid = threadIdx.x;
  const int bm = blockIdx.y * BM;
  const int bn = blockIdx.x * BN;
  const int tr = (tid >> 4) << 2;
  const int tc = (tid & 15) << 2;
  const int ar = tid >> 2;
  const int ac = (tid & 3) << 2;
  float acc[4][4] = {{0.0f}};
  float tmp[4];
  for (int k0 = 0; k0 < CC; k0 += BK) {
    ldv4(A + (size_t)(bm + ar) * CC + (k0 + ac), tmp);
    As[ac + 0][ar] = tmp[0]; As[ac + 1][ar] = tmp[1];
    As[ac + 2][ar] = tmp[2]; As[ac + 3][ar] = tmp[3];
    const int nn = tid >> 2;
    const int kx = (tid & 3) << 2;
    ldv4(W + (size_t)(bn + nn) * CC + (k0 + kx), tmp);
    Bs[kx + 0][nn] = tmp[0]; Bs[kx + 1][nn] = tmp[1];
    Bs[kx + 2][nn] = tmp[2]; Bs[kx + 3][nn] = tmp[3];
    __syncthreads();
#pragma unroll
    for (int kk = 0; kk < BK; ++kk) {
      const float a0 = As[kk][tr + 0], a1 = As[kk][tr + 1];
      const float a2 = As[kk][tr + 2], a3 = As[kk][tr + 3];
      const float b0 = Bs[kk][tc + 0], b1 = Bs[kk][tc + 1];
      const float b2 = Bs[kk][tc + 2], b3 = Bs[kk][tc + 3];
      acc[0][0] += a0 * b0; acc[0][1] += a0 * b1; acc[0][2] += a0 * b2; acc[0][3] += a0 * b3;
      acc[1][0] += a1 * b0; acc[1][1] += a1 * b1; acc[1][2] += a1 * b2; acc[1][3] += a1 * b3;
      acc[2][0] += a2 * b0; acc[2][1] += a2 * b1; acc[2][2] += a2 * b2; acc[2][3] += a2 * b3;
      acc[3][0] += a3 * b0; acc[3][1] += a3 * b1; acc[3][2] += a3 * b2; acc[3][3] += a3 * b3;
    }
    __syncthreads();
  }
#pragma unroll
  for (int i = 0; i < 4; ++i) {
    const int row = bm + tr + i;
    const int b = row >> 10;
    const int t = row & (TT - 1);
    const int len = xlen[b];
#pragma unroll
    for (int j = 0; j < 4; ++j) {
      const int o = bn + tc + j;
      float vv = acc[i][j] + bias[o];
      if (t >= len) vv = 0.0f;
      const size_t dst = (o < OUTD)
          ? (size_t)OFF_M    + ((size_t)b * OUTD + o) * TT + t
          : (size_t)OFF_LOGS + ((size_t)b * OUTD + (o - OUTD)) * TT + t;
      out[dst] = vv;
    }
  }
}

// ---------------- Output packing ----------------
__global__ __launch_bounds__(256) void pack_xbct_k(
    const float* __restrict__ X, float* __restrict__ out)
{
  const int i = blockIdx.x * 256 + threadIdx.x;
  const int b = i >> 18;
  const int c = (i >> 10) & (CC - 1);
  const int t = i & (TT - 1);
  out[OFF_XBCT + i] = X[((size_t)b << 18) + ((size_t)t << 8) + c];
}

__global__ __launch_bounds__(256) void pack_mask_k(
    const int* __restrict__ xlen, float* __restrict__ out)
{
  const int i = blockIdx.x * 256 + threadIdx.x;
  const int b = i >> 10;
  const int t = i & (TT - 1);
  out[OFF_MASK + i] = (t < xlen[b]) ? 1.0f : 0.0f;
}

extern "C" void kernel_launch(void* const* d_in, const int* in_sizes, int n_in,
                              void* d_out, int out_size, void* d_ws, size_t ws_size,
                              hipStream_t stream)
{
  (void)in_sizes; (void)n_in; (void)out_size; (void)ws_size;
  const float* emb   = (const float*)d_in[0];
  const float* Wq    = (const float*)d_in[1];
  const float* Wk    = (const float*)d_in[2];
  const float* Wv    = (const float*)d_in[3];
  const float* Wo    = (const float*)d_in[4];
  const float* bq    = (const float*)d_in[5];
  const float* bk    = (const float*)d_in[6];
  const float* bv    = (const float*)d_in[7];
  const float* bo    = (const float*)d_in[8];
  const float* relk  = (const float*)d_in[9];
  const float* relv  = (const float*)d_in[10];
  const float* ln1g  = (const float*)d_in[11];
  const float* ln1b  = (const float*)d_in[12];
  const float* ln2g  = (const float*)d_in[13];
  const float* ln2b  = (const float*)d_in[14];
  const float* W1    = (const float*)d_in[15];
  const float* b1    = (const float*)d_in[16];
  const float* W2    = (const float*)d_in[17];
  const float* b2    = (const float*)d_in[18];
  const float* projw = (const float*)d_in[19];
  const float* projb = (const float*)d_in[20];
  const int*   tokens = (const int*)d_in[21];
  const int*   xlen   = (const int*)d_in[22];
  float* out = (float*)d_out;

  float* X  = (float*)d_ws;
  u16* pool = (u16*)(X + (size_t)BT * CC);
  u16* Qb = pool;
  u16* Hc = pool;
  float* Ob = out + OFF_XBCT;
  u16*   Kb = (u16*)(out + OFF_M);
  u16*   Vb = (u16*)(out + OFF_LOGS);
  float* T5 = out + OFF_M;

  embed_k<<<(BT * CC) / 256, 256, 0, stream>>>(emb, tokens, X);

  const dim3 gC(CC / 64, BT / 64);
  const dim3 gA(16, BB * HH);
  const dim3 gP((2 * OUTD) / BN, BT / BM);

  for (int l = 0; l < LL; ++l) {
    const float* Wq_l = Wq + (size_t)l * CC * CC;
    const float* Wk_l = Wk + (size_t)l * CC * CC;
    const float* Wv_l = Wv + (size_t)l * CC * CC;
    const float* Wo_l = Wo + (size_t)l * CC * CC;
    const float* rk_l = relk + (size_t)l * (2 * WSZ + 1) * HD;
    const float* rv_l = relv + (size_t)l * (2 * WSZ + 1) * HD;

    gemm_m_k<float, u16><<<gC, 256, 0, stream>>>(X, Wq_l, CC, bq + (size_t)l * CC,
                                                 Qb, CC, CC, 0.125f, 0, 0);
    gemm_m_k<float, u16><<<gC, 256, 0, stream>>>(X, Wk_l, CC, bk + (size_t)l * CC,
                                                 Kb, CC, CC, 1.0f, 0, 0);
    gemm_m_k<float, u16><<<gC, 256, 0, stream>>>(X, Wv_l, CC, bv + (size_t)l * CC,
                                                 Vb, CC, CC, 1.0f, 0, 0);
    fattn_k<<<gA, 256, 0, stream>>>(Qb, Kb, Vb, rk_l, rv_l, xlen, Ob);
    gemm_m_k<float, float><<<gC, 256, 0, stream>>>(Ob, Wo_l, CC, bo + (size_t)l * CC,
                                                   T5, CC, CC, 1.0f, 0, 0);
    addln_k<<<BT, 256, 0, stream>>>(X, T5, ln1g + (size_t)l * CC,
                                    ln1b + (size_t)l * CC, xlen, 0);
    for (int c = 0; c < 4; ++c) {
      gemm_m_k<float, u16><<<gC, 256, 0, stream>>>(X, W1 + (size_t)l * CC * FCD + c * 256,
                                                   FCD, b1 + (size_t)l * FCD + c * 256,
                                                   Hc, 256, CC, 1.0f, 1, 0);
      gemm_m_k<u16, float><<<gC, 256, 0, stream>>>(Hc,
                                                   W2 + (size_t)l * FCD * CC + (size_t)c * 256 * CC,
                                                   CC, (c == 0) ? (b2 + (size_t)l * CC) : nullptr,
                                                   T5, CC, 256, 1.0f, 0, (c > 0));
    }
    addln_k<<<BT, 256, 0, stream>>>(X, T5, ln2g + (size_t)l * CC,
                                    ln2b + (size_t)l * CC, xlen, 1);
  }

  proj_k<<<gP, 256, 0, stream>>>(X, projw, projb, xlen, out);
  pack_xbct_k<<<(BB * CC * TT) / 256, 256, 0, stream>>>(X, out);
  pack_mask_k<<<(BB * TT) / 256, 256, 0, stream>>>(xlen, out);
}